// Round 6
// baseline (5356.893 us; speedup 1.0000x reference)
//
#include <hip/hip_runtime.h>
#include <hip/hip_bf16.h>
#include <math.h>

// Problem constants (fixed by setup_inputs)
#define Bb   32
#define Ll   30
#define Hh   300
#define Pp   8
#define Nn   16384
#define Ee   131072
#define NPG  512
#define NI   5

typedef __attribute__((ext_vector_type(4))) float f32x4;
typedef __attribute__((ext_vector_type(8))) short s16x8;

__device__ __forceinline__ float eluf(float x){ return x > 0.f ? x : expm1f(x); }
__device__ __forceinline__ float sigf(float x){ return 1.f/(1.f+expf(-x)); }
__device__ __forceinline__ float wave_sum(float s){
    s += __shfl_xor(s, 32); s += __shfl_xor(s, 16); s += __shfl_xor(s, 8);
    s += __shfl_xor(s, 4);  s += __shfl_xor(s, 2);  s += __shfl_xor(s, 1);
    return s;
}
__device__ __forceinline__ unsigned short f2bf(float x){
    unsigned u = __float_as_uint(x);
    unsigned r = u + 0x7FFFu + ((u >> 16) & 1u);
    return (unsigned short)(r >> 16);
}
__device__ __forceinline__ float bf2f(unsigned short v){
    return __uint_as_float(((unsigned)v) << 16);
}

// ---------------------------------------------------------------------------
// A-tile fetch: fills a8 (A values as f32) and s8 (scale values).
// BFA=true: A is bf16, padded pitch, no bounds checks (pitch = NTILES*32).
// ---------------------------------------------------------------------------
template<int KK, bool BFA>
__device__ __forceinline__ void fetch_as(const float* __restrict__ arowf,
                                         const unsigned short* __restrict__ arowb,
                                         const float* __restrict__ srow,
                                         int k, float* a8, float* s8)
{
    if constexpr (BFA) {
        s16x8 av = *(const s16x8*)(arowb + k);
        float4 w0 = *(const float4*)(srow + k), w1 = *(const float4*)(srow + k + 4);
        s8[0]=w0.x; s8[1]=w0.y; s8[2]=w0.z; s8[3]=w0.w; s8[4]=w1.x; s8[5]=w1.y; s8[6]=w1.z; s8[7]=w1.w;
        #pragma unroll
        for (int j = 0; j < 8; j++) a8[j] = bf2f((unsigned short)av[j]);
    } else {
        if (k + 8 <= KK) {
            float4 v0 = *(const float4*)(arowf + k), v1 = *(const float4*)(arowf + k + 4);
            a8[0]=v0.x; a8[1]=v0.y; a8[2]=v0.z; a8[3]=v0.w; a8[4]=v1.x; a8[5]=v1.y; a8[6]=v1.z; a8[7]=v1.w;
            float4 w0 = *(const float4*)(srow + k), w1 = *(const float4*)(srow + k + 4);
            s8[0]=w0.x; s8[1]=w0.y; s8[2]=w0.z; s8[3]=w0.w; s8[4]=w1.x; s8[5]=w1.y; s8[6]=w1.z; s8[7]=w1.w;
        } else {
            #pragma unroll
            for (int j = 0; j < 8; j++){ int kk = k + j; a8[j] = (kk < KK) ? arowf[kk] : 0.f; s8[j] = (kk < KK) ? srow[kk] : 0.f; }
        }
    }
}

// ---------------------------------------------------------------------------
// MFMA scored-GEMM, 2-phase pipelined, A and B both LDS-staged (double-buffered).
// out[m] = sum_c elu( sum_k A[m,k]*S[rowb[m],k] * B[k,c] ) * w[c]
// Bt: bf16 transposed [304][BPITCH] ([col][k]) zero-padded.
// Block: 256 thr = 4 waves (2x2). 64 rows x 304 cols per block. BK=32.
// ---------------------------------------------------------------------------
template<int KK, int BPITCH, int NTILES, bool BFA>
__device__ __forceinline__ void mfma_score_impl(
    const float* __restrict__ Af, const unsigned short* __restrict__ Ab, int lda,
    const unsigned short* __restrict__ Bt,
    const float* __restrict__ S, int sstride, const int* __restrict__ rowb,
    const float* __restrict__ wpad,
    float* __restrict__ out)
{
    __shared__ unsigned short As[2][64*40];
    __shared__ unsigned short Bs[2][304*36];
    __shared__ float red[2][2][32];

    const int t = threadIdx.x;
    const int wave = t >> 6, lane = t & 63;
    const int wr = wave >> 1, wc = wave & 1;
    const int rowBlock = blockIdx.x * 64;

    const int sr = t >> 2;            // A staging row 0..63
    const int sk = (t & 3) * 8;       // A staging k sub-offset
    const int grow = rowBlock + sr;
    const int bb = rowb[grow];
    const float* arowf = nullptr;
    const unsigned short* arowb = nullptr;
    if constexpr (BFA) arowb = Ab + (size_t)grow * lda;
    else               arowf = Af + (size_t)grow * lda;
    const float* srow = S + (size_t)bb * sstride;

    f32x4 acc[2][10];
    #pragma unroll
    for (int rt = 0; rt < 2; rt++)
        #pragma unroll
        for (int ct = 0; ct < 10; ct++) acc[rt][ct] = (f32x4){0.f,0.f,0.f,0.f};

    float a8[8], s8[8];
    s16x8 bvec[5];

    // ---- prologue: load + store tile 0 ----
    {
        fetch_as<KK, BFA>(arowf, arowb, srow, sk, a8, s8);
        #pragma unroll
        for (int i = 0; i < 5; i++){
            int v = t + 256 * i;
            if (v < 1216) bvec[i] = *(const s16x8*)&Bt[(size_t)(v >> 2) * BPITCH + ((v & 3) * 8)];
        }
        s16x8 pv;
        #pragma unroll
        for (int j = 0; j < 8; j++) pv[j] = (short)f2bf(a8[j] * s8[j]);
        *(s16x8*)&As[0][sr * 40 + sk] = pv;
        #pragma unroll
        for (int i = 0; i < 5; i++){
            int v = t + 256 * i;
            if (v < 1216) *(s16x8*)&Bs[0][(v >> 2) * 36 + ((v & 3) * 8)] = bvec[i];
        }
    }
    __syncthreads();

    int cur = 0;
    for (int kt = 0; kt < NTILES; ++kt) {
        // issue next-tile global loads (stay in flight across MFMA phase)
        if (kt + 1 < NTILES) {
            fetch_as<KK, BFA>(arowf, arowb, srow, (kt + 1) * 32 + sk, a8, s8);
            int k0 = (kt + 1) * 32;
            #pragma unroll
            for (int i = 0; i < 5; i++){
                int v = t + 256 * i;
                if (v < 1216) bvec[i] = *(const s16x8*)&Bt[(size_t)(v >> 2) * BPITCH + k0 + ((v & 3) * 8)];
            }
        }
        // MFMA phase from buf[cur]
        s16x8 af0 = *(s16x8*)&As[cur][(wr * 32 + (lane & 15)) * 40 + (lane >> 4) * 8];
        s16x8 af1 = *(s16x8*)&As[cur][(wr * 32 + 16 + (lane & 15)) * 40 + (lane >> 4) * 8];
        #pragma unroll
        for (int ct = 0; ct < 10; ct++) {
            if (wc == 1 && ct == 9) continue;
            int col = wc * 160 + ct * 16 + (lane & 15);
            s16x8 bf = *(s16x8*)&Bs[cur][col * 36 + (lane >> 4) * 8];
            acc[0][ct] = __builtin_amdgcn_mfma_f32_16x16x32_bf16(af0, bf, acc[0][ct], 0, 0, 0);
            acc[1][ct] = __builtin_amdgcn_mfma_f32_16x16x32_bf16(af1, bf, acc[1][ct], 0, 0, 0);
        }
        // write next tile into the other buffer
        if (kt + 1 < NTILES) {
            s16x8 pv;
            #pragma unroll
            for (int j = 0; j < 8; j++) pv[j] = (short)f2bf(a8[j] * s8[j]);
            *(s16x8*)&As[cur ^ 1][sr * 40 + sk] = pv;
            #pragma unroll
            for (int i = 0; i < 5; i++){
                int v = t + 256 * i;
                if (v < 1216) *(s16x8*)&Bs[cur ^ 1][(v >> 2) * 36 + ((v & 3) * 8)] = bvec[i];
            }
        }
        __syncthreads();
        cur ^= 1;
    }

    // ---- epilogue: per-row sum of elu(C)*w ----
    float p[2][4];
    #pragma unroll
    for (int rt = 0; rt < 2; rt++)
        #pragma unroll
        for (int i = 0; i < 4; i++) p[rt][i] = 0.f;
    #pragma unroll
    for (int ct = 0; ct < 10; ct++) {
        if (wc == 1 && ct == 9) continue;
        int col = wc * 160 + ct * 16 + (lane & 15);
        float wv = wpad[col];
        #pragma unroll
        for (int rt = 0; rt < 2; rt++)
            #pragma unroll
            for (int i = 0; i < 4; i++)
                p[rt][i] += eluf(acc[rt][ct][i]) * wv;
    }
    #pragma unroll
    for (int m = 1; m <= 8; m <<= 1) {
        #pragma unroll
        for (int rt = 0; rt < 2; rt++)
            #pragma unroll
            for (int i = 0; i < 4; i++)
                p[rt][i] += __shfl_xor(p[rt][i], m);
    }
    if ((lane & 15) == 0) {
        int q = lane >> 4;
        #pragma unroll
        for (int rt = 0; rt < 2; rt++)
            #pragma unroll
            for (int i = 0; i < 4; i++)
                red[wr][wc][rt * 16 + q * 4 + i] = p[rt][i];
    }
    __syncthreads();
    if (t < 64) {
        int wrr = t >> 5, r = t & 31;
        out[rowBlock + wrr * 32 + r] = red[wrr][0][r] + red[wrr][1][r];
    }
}

// bf16-A variants
__global__ __launch_bounds__(256, 2) void mfma_node_k(
    const unsigned short* __restrict__ Ab, const unsigned short* __restrict__ Bt,
    const float* __restrict__ S, const int* __restrict__ rowb,
    const float* __restrict__ wpad, float* __restrict__ out)
{
    mfma_score_impl<2400, 2400, 75, true>(nullptr, Ab, 2400, Bt, S, 2400, rowb, wpad, out);
}
__global__ __launch_bounds__(256, 2) void mfma_edge_k(
    const unsigned short* __restrict__ Ab, const unsigned short* __restrict__ Bt,
    const float* __restrict__ S, const int* __restrict__ rowb,
    const float* __restrict__ wpad, float* __restrict__ out)
{
    mfma_score_impl<320, 320, 10, true>(nullptr, Ab, 320, Bt, S, NI * 300, rowb, wpad, out);
}
// f32-A fallbacks (small-ws path)
__global__ __launch_bounds__(256, 2) void mfma_node_f_k(
    const float* __restrict__ A, const unsigned short* __restrict__ Bt,
    const float* __restrict__ S, const int* __restrict__ rowb,
    const float* __restrict__ wpad, float* __restrict__ out)
{
    mfma_score_impl<2400, 2400, 75, false>(A, nullptr, 2400, Bt, S, 2400, rowb, wpad, out);
}
__global__ __launch_bounds__(256, 2) void mfma_edge_f_k(
    const float* __restrict__ A, const unsigned short* __restrict__ Bt,
    const float* __restrict__ S, const int* __restrict__ rowb,
    const float* __restrict__ wpad, float* __restrict__ out)
{
    mfma_score_impl<300, 320, 10, false>(A, nullptr, 300, Bt, S, NI * 300, rowb, wpad, out);
}

// Convert f32 [rows][K] -> bf16 [rows][pitch], zero-padded. 8 elems/thread.
__global__ void cvt_attr8_k(const float* __restrict__ src, long rows, int K, int pitch,
                            unsigned short* __restrict__ dst)
{
    const int pg = pitch >> 3;
    long total = rows * pg;
    for (long i = (long)blockIdx.x * blockDim.x + threadIdx.x; i < total;
         i += (long)gridDim.x * blockDim.x) {
        long r = i / pg;
        int kg = (int)(i - r * pg) * 8;
        s16x8 v;
        #pragma unroll
        for (int j = 0; j < 8; j++){
            int k = kg + j;
            float x = (k < K) ? src[r * (long)K + k] : 0.f;
            v[j] = (short)f2bf(x);
        }
        *(s16x8*)&dst[r * (long)pitch + kg] = v;
    }
}

__global__ void build_bt_k(const float* __restrict__ B, int K, int N, int bpitch,
                           unsigned short* __restrict__ Bt)
{
    int idx = blockIdx.x * 256 + threadIdx.x;
    if (idx >= 304 * bpitch) return;
    int col = idx / bpitch, k = idx - col * bpitch;
    float v = (col < N && k < K) ? B[(size_t)k * N + col] : 0.f;
    Bt[idx] = f2bf(v);
}

__global__ void wpad_k(const float* __restrict__ wn, const float* __restrict__ wr,
                       float* __restrict__ wnp, float* __restrict__ wrp)
{
    int i = threadIdx.x;
    if (i < 304) { wnp[i] = (i < 300) ? wn[i] : 0.f; wrp[i] = (i < 300) ? wr[i] : 0.f; }
}

// ---------------------------------------------------------------------------
// Parallel f32 GEMM: 64x64 tile, 256 threads, 4x4 per thread, optional split-K.
// ---------------------------------------------------------------------------
template<bool BT, int EPI>
__global__ __launch_bounds__(256) void gemm2_k(
    const float* __restrict__ A, int lda, int M, int K, int kChunk,
    const float* __restrict__ Bm, int ldb, int N,
    float* __restrict__ C)
{
    __shared__ float As[16][68];
    __shared__ float Bs[16][68];
    const int t = threadIdx.x;
    const int rowBlock = blockIdx.x * 64, colBase = blockIdx.y * 64;
    const int k0 = blockIdx.z * kChunk;
    const int kend = min(K, k0 + kChunk);

    float acc[4][4] = {{0.f}};
    const int am = t >> 2, ak4 = (t & 3) * 4;
    const int tx = t & 15, ty = t >> 4;

    for (int kt = k0; kt < kend; kt += 16) {
        {
            int gr = rowBlock + am;
            #pragma unroll
            for (int j = 0; j < 4; j++) {
                int gk = kt + ak4 + j;
                As[ak4 + j][am] = (gr < M && gk < kend) ? A[(size_t)gr * lda + gk] : 0.f;
            }
        }
        if (!BT) {
            int bk = t >> 4, bcc = (t & 15) * 4;
            int gk = kt + bk;
            #pragma unroll
            for (int j = 0; j < 4; j++) {
                int gc = colBase + bcc + j;
                Bs[bk][bcc + j] = (gk < kend && gc < N) ? Bm[(size_t)gk * ldb + gc] : 0.f;
            }
        } else {
            int bc = t >> 2, bk4 = (t & 3) * 4;
            int gc = colBase + bc;
            #pragma unroll
            for (int j = 0; j < 4; j++) {
                int gk = kt + bk4 + j;
                Bs[bk4 + j][bc] = (gk < kend && gc < N) ? Bm[(size_t)gc * ldb + gk] : 0.f;
            }
        }
        __syncthreads();
        #pragma unroll
        for (int kk = 0; kk < 16; kk++) {
            float4 a4 = *(float4*)&As[kk][ty * 4];
            float4 b4 = *(float4*)&Bs[kk][tx * 4];
            float av[4] = {a4.x, a4.y, a4.z, a4.w};
            float bv[4] = {b4.x, b4.y, b4.z, b4.w};
            #pragma unroll
            for (int r = 0; r < 4; r++)
                #pragma unroll
                for (int c = 0; c < 4; c++)
                    acc[r][c] = fmaf(av[r], bv[c], acc[r][c]);
        }
        __syncthreads();
    }

    #pragma unroll
    for (int r = 0; r < 4; r++) {
        int row = rowBlock + ty * 4 + r;
        if (row >= M) continue;
        #pragma unroll
        for (int c = 0; c < 4; c++) {
            int col = colBase + tx * 4 + c;
            if (col >= N) continue;
            if (EPI == 0) C[(size_t)row * N + col] = acc[r][c];
            else atomicAdd(&C[(size_t)row * N + col], acc[r][c]);
        }
    }
}

template<int EPI>
__global__ void mm_naive_bt_k(const float* __restrict__ A, int lda, int M, int K,
                              const float* __restrict__ Bm, int N,
                              const float* __restrict__ bias,
                              float* __restrict__ Cf)
{
    int idx = blockIdx.x * 256 + threadIdx.x;
    if (idx >= M * N) return;
    int m = idx / N;
    int j = idx - m * N;
    const float* arow = A + (size_t)m * lda;
    const float* brow = Bm + (size_t)j * K;
    float s = 0.f;
    for (int k = 0; k < K; k++) s += arow[k] * brow[k];
    if (EPI == 0) Cf[idx] = s;
    else if (EPI == 2) Cf[idx] = eluf(s + bias[j]);
    else Cf[idx] = s + bias[j];
}

__global__ void transpose_k(const float* __restrict__ src, int R, int C,
                            float* __restrict__ dst)
{
    int idx = blockIdx.x * 256 + threadIdx.x;
    if (idx >= R * C) return;
    int r = idx / C, c = idx - r * C;
    dst[(size_t)c * R + r] = src[idx];
}

// Pack lstm Whh [1200][300] -> bf16 k-major WT[k][1200]
__global__ void pack_whhT_k(const float* __restrict__ W, unsigned short* __restrict__ WT)
{
    int idx = blockIdx.x * 256 + threadIdx.x;
    if (idx >= 300 * 1200) return;
    int k = idx / 1200, r = idx - k * 1200;
    WT[idx] = f2bf(W[(size_t)r * 300 + k]);
}

// ---------------------------------------------------------------------------
__global__ void vocab_build_k(const float* __restrict__ cv, const float* __restrict__ td,
                              float* __restrict__ ve)
{
    int idx = blockIdx.x * 256 + threadIdx.x;
    if (idx < 2001 * 300) ve[idx] = (idx < 2000 * 300) ? cv[idx] : td[idx - 2000 * 300];
}

__global__ void softmax_rows_k(float* __restrict__ X, int nc)
{
    int row = blockIdx.x, t = threadIdx.x;
    __shared__ float red[256];
    size_t base = (size_t)row * nc;
    float m = -3.4e38f;
    for (int i = t; i < nc; i += 256) m = fmaxf(m, X[base + i]);
    red[t] = m; __syncthreads();
    for (int s = 128; s > 0; s >>= 1){ if (t < s) red[t] = fmaxf(red[t], red[t+s]); __syncthreads(); }
    float mx = red[0]; __syncthreads();
    float sm = 0.f;
    for (int i = t; i < nc; i += 256){ float e = expf(X[base + i] - mx); X[base + i] = e; sm += e; }
    red[t] = sm; __syncthreads();
    for (int s = 128; s > 0; s >>= 1){ if (t < s) red[t] += red[t+s]; __syncthreads(); }
    float inv = 1.f / red[0];
    for (int i = t; i < nc; i += 256) X[base + i] *= inv;
}

__global__ void tagged_add_k(const float* __restrict__ sim, const float* __restrict__ q,
                             float* __restrict__ tg)
{
    int idx = blockIdx.x * 256 + threadIdx.x;
    if (idx >= 960 * 300) return;
    int row = idx / 300;
    tg[idx] += sim[(size_t)row * 2001 + 2000] * q[idx];
}

// Fast persistent LSTM: 1 block/batch, 640 threads (10 waves).
// Threads 0..599 each own 2 gate rows (2t, 2t+1); threads 0..299 own hid t.
// WT: bf16 [300][1200] k-major. Deep 2-stage prefetch pipeline (20 in flight).
__global__ __launch_bounds__(640) void lstm_fast_k(
    const float* __restrict__ xW, const unsigned short* __restrict__ WT,
    const float* __restrict__ bih, const float* __restrict__ bhh,
    const int* __restrict__ lengths, float* __restrict__ encoded)
{
    __shared__ __align__(16) float hs[304];
    __shared__ float gs[1200];
    const int b = blockIdx.x, t = threadIdx.x;
    const int len = lengths[b];
    const bool ga = t < 600;
    const bool ha = t < 300;
    float bs0 = 0.f, bs1 = 0.f;
    if (ga) { bs0 = bih[2*t] + bhh[2*t]; bs1 = bih[2*t+1] + bhh[2*t+1]; }
    if (ha) hs[t] = 0.f;
    float c = 0.f, h = 0.f;
    __syncthreads();
    const float* xb = xW + (size_t)b * Ll * 1200;
    const unsigned* wp = (const unsigned*)WT + t;   // wp[k*600] = rows (2t,2t+1) at k
    for (int st = 0; st < len; ++st) {
        if (ga) {
            float d0 = 0.f, d1 = 0.f;
            unsigned bufA[20], bufB[20];
            #pragma unroll
            for (int j = 0; j < 20; j++) bufA[j] = wp[j * 600];
            // 15 chunks of 20 k's, 2-stage software pipeline (static indices only)
            #pragma unroll
            for (int kc = 0; kc < 15; kc += 2) {
                // phase A: prefetch chunk kc+1, compute chunk kc from bufA
                if (kc + 1 < 15) {
                    #pragma unroll
                    for (int j = 0; j < 20; j++) bufB[j] = wp[(kc + 1) * 12000 + j * 600];
                }
                {
                    float hv[20];
                    #pragma unroll
                    for (int q = 0; q < 5; q++) {
                        float4 hq = *(const float4*)&hs[kc * 20 + q * 4];
                        hv[q*4+0]=hq.x; hv[q*4+1]=hq.y; hv[q*4+2]=hq.z; hv[q*4+3]=hq.w;
                    }
                    #pragma unroll
                    for (int j = 0; j < 20; j++) {
                        unsigned wv = bufA[j];
                        d0 = fmaf(hv[j], __uint_as_float(wv << 16), d0);
                        d1 = fmaf(hv[j], __uint_as_float(wv & 0xFFFF0000u), d1);
                    }
                }
                // phase B: prefetch chunk kc+2, compute chunk kc+1 from bufB
                if (kc + 1 < 15) {
                    if (kc + 2 < 15) {
                        #pragma unroll
                        for (int j = 0; j < 20; j++) bufA[j] = wp[(kc + 2) * 12000 + j * 600];
                    }
                    float hv[20];
                    #pragma unroll
                    for (int q = 0; q < 5; q++) {
                        float4 hq = *(const float4*)&hs[(kc + 1) * 20 + q * 4];
                        hv[q*4+0]=hq.x; hv[q*4+1]=hq.y; hv[q*4+2]=hq.z; hv[q*4+3]=hq.w;
                    }
                    #pragma unroll
                    for (int j = 0; j < 20; j++) {
                        unsigned wv = bufB[j];
                        d0 = fmaf(hv[j], __uint_as_float(wv << 16), d0);
                        d1 = fmaf(hv[j], __uint_as_float(wv & 0xFFFF0000u), d1);
                    }
                }
            }
            float2 xv = *(const float2*)(xb + st * 1200 + 2 * t);
            gs[2*t]   = xv.x + bs0 + d0;
            gs[2*t+1] = xv.y + bs1 + d1;
        }
        __syncthreads();
        if (ha) {
            float i_ = sigf(gs[t]);
            float f_ = sigf(gs[300 + t]);
            float g_ = tanhf(gs[600 + t]);
            float o_ = sigf(gs[900 + t]);
            c = f_ * c + i_ * g_;
            h = o_ * tanhf(c);
            hs[t] = h;
        }
        __syncthreads();
    }
    if (ha) encoded[b * 300 + t] = h;
}

// Persistent RNN decoder
__global__ __launch_bounds__(320) void rnn_all_k(
    const float* __restrict__ enc, const float* __restrict__ WihT,
    const float* __restrict__ WhhT,
    const float* __restrict__ bih, const float* __restrict__ bhh,
    float* __restrict__ hidden)
{
    __shared__ float es[304];
    __shared__ float hs[304];
    const int b = blockIdx.x, i = threadIdx.x;
    const bool act = i < 300;
    if (act) { es[i] = enc[b * 300 + i]; hs[i] = 0.f; }
    __syncthreads();
    float ex = 0.f;
    if (act) {
        #pragma unroll 8
        for (int k = 0; k < 300; k++)
            ex = fmaf(es[k], WihT[(size_t)k * 300 + i], ex);
        ex += bih[i] + bhh[i];
    }
    for (int it = 0; it < NI; it++) {
        __syncthreads();
        float d = 0.f;
        if (act) {
            #pragma unroll 8
            for (int k = 0; k < 300; k++)
                d = fmaf(hs[k], WhhT[(size_t)k * 300 + i], d);
        }
        float v = fmaxf(ex + d, 0.f);
        __syncthreads();
        if (act) { hs[i] = v; hidden[((size_t)b * NI + it) * 300 + i] = v; }
    }
}

__global__ __launch_bounds__(256) void scores_instr_k(
    const float* __restrict__ hidden, const float* __restrict__ tagged,
    const int* __restrict__ lengths, float* __restrict__ instr)
{
    __shared__ float sc[4][32];
    int wv = threadIdx.x >> 6;
    int wid = blockIdx.x * 4 + wv;
    int lane = threadIdx.x & 63;
    int b = wid / NI;
    const float* hr = hidden + (size_t)wid * Hh;
    float hv[5];
    #pragma unroll
    for (int p = 0; p < 5; p++){ int k = lane + p * 64; hv[p] = (k < Hh) ? hr[k] : 0.f; }
    int len = lengths[b];
    for (int l = 0; l < Ll; l++){
        const float* trw = tagged + ((size_t)b * Ll + l) * Hh;
        float s = 0.f;
        #pragma unroll
        for (int p = 0; p < 5; p++){ int k = lane + p * 64; if (k < Hh) s += hv[p] * trw[k]; }
        s = wave_sum(s);
        if (lane == 0) sc[wv][l] = s;
    }
    __syncthreads();
    float mx = -3.4e38f;
    for (int l = 0; l < len; l++) mx = fmaxf(mx, sc[wv][l]);
    float sum = 0.f;
    for (int l = 0; l < len; l++) sum += expf(sc[wv][l] - mx);
    float inv = 1.f / sum;
    float a[5] = {0.f,0.f,0.f,0.f,0.f};
    for (int l = 0; l < len; l++){
        float pl = expf(sc[wv][l] - mx) * inv;
        const float* trw = tagged + ((size_t)b * Ll + l) * Hh;
        #pragma unroll
        for (int p = 0; p < 5; p++){ int k = lane + p * 64; if (k < Hh) a[p] += pl * trw[k]; }
    }
    #pragma unroll
    for (int p = 0; p < 5; p++){ int k = lane + p * 64; if (k < Hh) instr[(size_t)wid * Hh + k] = a[p]; }
}

__global__ __launch_bounds__(256) void prop_softmax_k(
    const float* __restrict__ instr, int ii, const float* __restrict__ pemb,
    float* __restrict__ psim, float* __restrict__ rsim)
{
    int wid = blockIdx.x * 4 + (threadIdx.x >> 6);
    int lane = threadIdx.x & 63;
    const float* ir = instr + ((size_t)wid * NI + ii) * Hh;
    float iv[5];
    #pragma unroll
    for (int p = 0; p < 5; p++){ int k = lane + p * 64; iv[p] = (k < Hh) ? ir[k] : 0.f; }
    float e[9];
    #pragma unroll
    for (int j = 0; j < 9; j++){
        const float* pr = pemb + j * Hh;
        float s = 0.f;
        #pragma unroll
        for (int p = 0; p < 5; p++){ int k = lane + p * 64; if (k < Hh) s += iv[p] * pr[k]; }
        e[j] = wave_sum(s);
    }
    if (lane == 0){
        float mx = e[0];
        #pragma unroll
        for (int j = 1; j < 9; j++) mx = fmaxf(mx, e[j]);
        float sum = 0.f;
        #pragma unroll
        for (int j = 0; j < 9; j++){ e[j] = expf(e[j] - mx); sum += e[j]; }
        float inv = 1.f / sum;
        #pragma unroll
        for (int p = 0; p < 8; p++) psim[wid * 8 + p] = e[p] * inv;
        rsim[wid] = e[8] * inv;
    }
}

__global__ void iscale_k(const float* __restrict__ instr, int step,
                         const float* __restrict__ psim, float* __restrict__ iscale)
{
    int idx = blockIdx.x * 256 + threadIdx.x;
    if (idx >= Bb * 2400) return;
    int b = idx / 2400; int k = idx - b * 2400;
    int p = k / 300;    int h = k - p * 300;
    iscale[idx] = instr[((size_t)b * NI + step) * Hh + h] * psim[b * 8 + p];
}

__global__ void count_k(const int* __restrict__ ni, int* __restrict__ cnt)
{
    int n = blockIdx.x * 256 + threadIdx.x;
    if (n < Nn) atomicAdd(&cnt[ni[n]], 1);
}
__global__ void dist_init_k(const int* __restrict__ ni, const int* __restrict__ cnt,
                            float* __restrict__ dist)
{
    int n = blockIdx.x * 256 + threadIdx.x;
    if (n < Nn) dist[n] = 1.f / (float)cnt[ni[n]];
}

__global__ void edge_msg_k(const int* __restrict__ ei, const float* __restrict__ es,
                           const float* __restrict__ dist, float* __restrict__ msgdot)
{
    int e = blockIdx.x * 256 + threadIdx.x;
    if (e < Ee){
        int s = ei[e];
        int d = ei[Ee + e];
        atomicAdd(&msgdot[d], dist[s] * es[e]);
    }
}

__global__ __launch_bounds__(256) void seg_update_k(
    const float* __restrict__ nscore, const float* __restrict__ msgdot,
    const float* __restrict__ rsim, float* __restrict__ dist)
{
    int b = blockIdx.x, t = threadIdx.x;
    __shared__ float red[256];
    int n0 = b * NPG;
    float a1 = nscore[n0 + t], a2 = nscore[n0 + 256 + t];
    float m1 = msgdot[n0 + t], m2 = msgdot[n0 + 256 + t];

    red[t] = fmaxf(a1, a2); __syncthreads();
    for (int s = 128; s > 0; s >>= 1){ if (t < s) red[t] = fmaxf(red[t], red[t+s]); __syncthreads(); }
    float mN = red[0]; __syncthreads();
    float e1 = expf(a1 - mN), e2 = expf(a2 - mN);
    red[t] = e1 + e2; __syncthreads();
    for (int s = 128; s > 0; s >>= 1){ if (t < s) red[t] += red[t+s]; __syncthreads(); }
    float sN = red[0]; __syncthreads();

    red[t] = fmaxf(m1, m2); __syncthreads();
    for (int s = 128; s > 0; s >>= 1){ if (t < s) red[t] = fmaxf(red[t], red[t+s]); __syncthreads(); }
    float mM = red[0]; __syncthreads();
    float f1 = expf(m1 - mM), f2 = expf(m2 - mM);
    red[t] = f1 + f2; __syncthreads();
    for (int s = 128; s > 0; s >>= 1){ if (t < s) red[t] += red[t+s]; __syncthreads(); }
    float sM = red[0];

    float rs = rsim[b];
    dist[n0 + t]       = rs * (f1 / sM) + (1.f - rs) * (e1 / sN);
    dist[n0 + 256 + t] = rs * (f2 / sM) + (1.f - rs) * (e2 / sN);
}

__global__ __launch_bounds__(320) void final_agg_k(
    const float* __restrict__ psim, const float* __restrict__ dist,
    const float* __restrict__ na, float* __restrict__ agg)
{
    int chunk = blockIdx.x;
    int b = blockIdx.y;
    int h = threadIdx.x;
    if (h >= Hh) return;
    float ps[8];
    #pragma unroll
    for (int p = 0; p < 8; p++) ps[p] = psim[b * 8 + p];
    float acc = 0.f;
    for (int i = 0; i < 32; i++){
        int n = b * NPG + chunk * 32 + i;
        const float* row = na + (size_t)n * Pp * Hh;
        float wsum = 0.f;
        #pragma unroll
        for (int p = 0; p < 8; p++) wsum += ps[p] * row[p * Hh + h];
        acc += dist[n] * wsum;
    }
    atomicAdd(&agg[b * Hh + h], acc);
}

__global__ void feats_k(const float* __restrict__ enc, const float* __restrict__ agg,
                        float* __restrict__ feats)
{
    int idx = blockIdx.x * 256 + threadIdx.x;
    if (idx >= Bb * 600) return;
    int b = idx / 600, j = idx - b * 600;
    feats[idx] = (j < 300) ? enc[b * 300 + j] : agg[b * 300 + (j - 300)];
}

// ---------------------------------------------------------------------------
extern "C" void kernel_launch(void* const* d_in, const int* in_sizes, int n_in,
                              void* d_out, int out_size, void* d_ws, size_t ws_size,
                              hipStream_t stream)
{
    const float* questions      = (const float*)d_in[0];
    const int*   lengths        = (const int*)  d_in[1];
    const int*   node_indices   = (const int*)  d_in[2];
    const int*   edge_indices   = (const int*)  d_in[3];
    const int*   edge_batch     = (const int*)  d_in[4];
    const float* node_attrs     = (const float*)d_in[5];
    const float* edge_attrs     = (const float*)d_in[6];
    const float* concept_vocab  = (const float*)d_in[7];
    const float* prop_emb       = (const float*)d_in[8];
    const float* tagger_default = (const float*)d_in[9];
    const float* tagger_weight  = (const float*)d_in[10];
    const float* lstm_Wih       = (const float*)d_in[11];
    const float* lstm_Whh       = (const float*)d_in[12];
    const float* lstm_bih       = (const float*)d_in[13];
    const float* lstm_bhh       = (const float*)d_in[14];
    const float* rnn_Wih        = (const float*)d_in[15];
    const float* rnn_Whh        = (const float*)d_in[16];
    const float* rnn_bih        = (const float*)d_in[17];
    const float* rnn_bhh        = (const float*)d_in[18];
    const float* Wnp            = (const float*)d_in[19];
    const float* Wedge          = (const float*)d_in[20];
    const float* w_nscore       = (const float*)d_in[21];
    const float* w_rscore       = (const float*)d_in[22];
    const float* fc1_W          = (const float*)d_in[23];
    const float* fc1_b          = (const float*)d_in[24];
    const float* fc2_W          = (const float*)d_in[25];
    const float* fc2_b          = (const float*)d_in[26];
    float* outf = (float*)d_out;

    float* ws = (float*)d_ws;
    size_t off = 0;
    auto alloc = [&](size_t n){ size_t r = off; off += (n + 63) & ~(size_t)63; return r; };
    size_t o_vocab  = alloc(2001 * 300);
    size_t o_q2     = alloc(960 * 300);
    size_t o_sim    = alloc((size_t)960 * 2001);
    size_t o_tagged = alloc(960 * 300);
    size_t o_xw     = alloc((size_t)960 * 1200);
    size_t o_enc    = alloc(9600);
    size_t o_hidden = alloc(48000);
    size_t o_instr  = alloc(48000);
    size_t o_psim   = alloc(256);
    size_t o_rsim   = alloc(64);
    size_t o_iscale = alloc((size_t)Bb * 2400);
    size_t o_nscore = alloc(Nn);
    size_t o_es     = alloc(Ee);
    size_t o_msgdot = alloc(Nn);
    size_t o_dist   = alloc(Nn);
    size_t o_cnt    = alloc(64);
    size_t o_agg    = alloc(9600);
    size_t o_feats  = alloc(19200);
    size_t o_z      = alloc(19200);
    size_t o_btn    = alloc((size_t)304 * 2400 / 2);   // Wnp^T bf16
    size_t o_bte    = alloc((size_t)304 * 320 / 2);    // Wedge^T bf16
    size_t o_wn     = alloc(304);
    size_t o_wr     = alloc(304);
    size_t o_wlstm  = alloc(180000);   // lstm Whh bf16 k-major [300][1200]
    size_t o_rwhhT  = alloc(90000);
    size_t o_rwihT  = alloc(90000);
    // big bf16 attr copies (gated on ws_size)
    size_t o_nab    = alloc((size_t)Nn * 2400 / 2);    // node_attrs bf16 [16384][2400]
    size_t o_eab    = alloc((size_t)Ee * 320 / 2);     // edge_attrs bf16 [131072][320]
    const bool bigws = ws_size >= off * sizeof(float);

    unsigned short* btn = (unsigned short*)(ws + o_btn);
    unsigned short* bte = (unsigned short*)(ws + o_bte);
    unsigned short* wlstm = (unsigned short*)(ws + o_wlstm);
    unsigned short* nab = (unsigned short*)(ws + o_nab);
    unsigned short* eab = (unsigned short*)(ws + o_eab);

    // ---- one-time conversions ----
    build_bt_k<<<(304*2400 + 255)/256, 256, 0, stream>>>(Wnp, 2400, 300, 2400, btn);
    build_bt_k<<<(304*320 + 255)/256, 256, 0, stream>>>(Wedge, 300, 300, 320, bte);
    wpad_k<<<1, 320, 0, stream>>>(w_nscore, w_rscore, ws + o_wn, ws + o_wr);
    pack_whhT_k<<<(300*1200 + 255)/256, 256, 0, stream>>>(lstm_Whh, wlstm);
    transpose_k<<<(300*300 + 255)/256, 256, 0, stream>>>(rnn_Whh, 300, 300, ws + o_rwhhT);
    transpose_k<<<(300*300 + 255)/256, 256, 0, stream>>>(rnn_Wih, 300, 300, ws + o_rwihT);
    vocab_build_k<<<(2001*300 + 255)/256, 256, 0, stream>>>(concept_vocab, tagger_default, ws + o_vocab);
    if (bigws) {
        cvt_attr8_k<<<2048, 256, 0, stream>>>(node_attrs, Nn, 2400, 2400, nab);
        cvt_attr8_k<<<2048, 256, 0, stream>>>(edge_attrs, Ee, 300, 320, eab);
    }

    // ---- tagger chain ----
    gemm2_k<false,0><<<dim3(15,5,1), 256, 0, stream>>>(
        questions, 300, 960, 300, 300, tagger_weight, 300, 300, ws + o_q2);
    gemm2_k<true,0><<<dim3(15,32,1), 256, 0, stream>>>(
        ws + o_q2, 300, 960, 300, 300, ws + o_vocab, 300, 2001, ws + o_sim);
    softmax_rows_k<<<960, 256, 0, stream>>>(ws + o_sim, 2001);
    hipMemsetAsync(ws + o_tagged, 0, 960 * 300 * sizeof(float), stream);
    gemm2_k<false,1><<<dim3(15,5,4), 256, 0, stream>>>(
        ws + o_sim, 2001, 960, 2000, 500, concept_vocab, 300, 300, ws + o_tagged);
    tagged_add_k<<<1125, 256, 0, stream>>>(ws + o_sim, questions, ws + o_tagged);

    // ---- LSTM ----
    gemm2_k<true,0><<<dim3(15,19,1), 256, 0, stream>>>(
        ws + o_tagged, 300, 960, 300, 300, lstm_Wih, 300, 1200, ws + o_xw);
    lstm_fast_k<<<Bb, 640, 0, stream>>>(ws + o_xw, wlstm, lstm_bih, lstm_bhh,
                                        lengths, ws + o_enc);

    // ---- RNN instruction decoder + instructions ----
    rnn_all_k<<<Bb, 320, 0, stream>>>(ws + o_enc, ws + o_rwihT, ws + o_rwhhT,
                                      rnn_bih, rnn_bhh, ws + o_hidden);
    scores_instr_k<<<40, 256, 0, stream>>>(ws + o_hidden, ws + o_tagged, lengths, ws + o_instr);

    // ---- distribution init ----
    hipMemsetAsync(ws + o_cnt, 0, 32 * sizeof(int), stream);
    count_k<<<64, 256, 0, stream>>>(node_indices, (int*)(ws + o_cnt));
    dist_init_k<<<64, 256, 0, stream>>>(node_indices, (int*)(ws + o_cnt), ws + o_dist);

    // ---- 4 message-passing steps ----
    for (int step = 0; step < 4; step++){
        prop_softmax_k<<<8, 256, 0, stream>>>(ws + o_instr, step, prop_emb, ws + o_psim, ws + o_rsim);
        iscale_k<<<300, 256, 0, stream>>>(ws + o_instr, step, ws + o_psim, ws + o_iscale);
        if (bigws) {
            mfma_node_k<<<Nn/64, 256, 0, stream>>>(
                nab, btn, ws + o_iscale, node_indices, ws + o_wn, ws + o_nscore);
            mfma_edge_k<<<Ee/64, 256, 0, stream>>>(
                eab, bte, ws + o_instr + step * 300, edge_batch, ws + o_wr, ws + o_es);
        } else {
            mfma_node_f_k<<<Nn/64, 256, 0, stream>>>(
                node_attrs, btn, ws + o_iscale, node_indices, ws + o_wn, ws + o_nscore);
            mfma_edge_f_k<<<Ee/64, 256, 0, stream>>>(
                edge_attrs, bte, ws + o_instr + step * 300, edge_batch, ws + o_wr, ws + o_es);
        }
        hipMemsetAsync(ws + o_msgdot, 0, Nn * sizeof(float), stream);
        edge_msg_k<<<512, 256, 0, stream>>>(edge_indices, ws + o_es, ws + o_dist, ws + o_msgdot);
        seg_update_k<<<32, 256, 0, stream>>>(ws + o_nscore, ws + o_msgdot, ws + o_rsim, ws + o_dist);
    }

    // ---- final aggregation + FCs ----
    prop_softmax_k<<<8, 256, 0, stream>>>(ws + o_instr, 4, prop_emb, ws + o_psim, ws + o_rsim);
    hipMemsetAsync(ws + o_agg, 0, 9600 * sizeof(float), stream);
    final_agg_k<<<dim3(16,32), 320, 0, stream>>>(ws + o_psim, ws + o_dist, node_attrs, ws + o_agg);
    feats_k<<<75, 256, 0, stream>>>(ws + o_enc, ws + o_agg, ws + o_feats);
    mm_naive_bt_k<2><<<75, 256, 0, stream>>>(
        ws + o_feats, 600, 32, 600, fc1_W, 600, fc1_b, ws + o_z);
    mm_naive_bt_k<3><<<(32*1845 + 255)/256, 256, 0, stream>>>(
        ws + o_z, 600, 32, 600, fc2_W, 1845, fc2_b, outf);
}

// Round 7
// 1949.155 us; speedup vs baseline: 2.7483x; 2.7483x over previous
//
#include <hip/hip_runtime.h>
#include <hip/hip_bf16.h>
#include <math.h>

// Problem constants (fixed by setup_inputs)
#define Bb   32
#define Ll   30
#define Hh   300
#define Pp   8
#define Nn   16384
#define Ee   131072
#define NPG  512
#define NI   5

typedef __attribute__((ext_vector_type(4))) float f32x4;
typedef __attribute__((ext_vector_type(8))) short s16x8;

__device__ __forceinline__ float eluf(float x){ return x > 0.f ? x : expm1f(x); }
__device__ __forceinline__ float sigf(float x){ return 1.f/(1.f+expf(-x)); }
__device__ __forceinline__ float wave_sum(float s){
    s += __shfl_xor(s, 32); s += __shfl_xor(s, 16); s += __shfl_xor(s, 8);
    s += __shfl_xor(s, 4);  s += __shfl_xor(s, 2);  s += __shfl_xor(s, 1);
    return s;
}
__device__ __forceinline__ unsigned short f2bf(float x){
    unsigned u = __float_as_uint(x);
    unsigned r = u + 0x7FFFu + ((u >> 16) & 1u);
    return (unsigned short)(r >> 16);
}
__device__ __forceinline__ float bf2f(unsigned short v){
    return __uint_as_float(((unsigned)v) << 16);
}

// ---------------------------------------------------------------------------
// A-tile fetch: fills a8 (A values as f32) and s8 (scale values).
// BFA=true: A is bf16, padded pitch, no bounds checks.
// ---------------------------------------------------------------------------
template<int KK, bool BFA>
__device__ __forceinline__ void fetch_as(const float* __restrict__ arowf,
                                         const unsigned short* __restrict__ arowb,
                                         const float* __restrict__ srow,
                                         int k, float* a8, float* s8)
{
    if constexpr (BFA) {
        s16x8 av = *(const s16x8*)(arowb + k);
        float4 w0 = *(const float4*)(srow + k), w1 = *(const float4*)(srow + k + 4);
        s8[0]=w0.x; s8[1]=w0.y; s8[2]=w0.z; s8[3]=w0.w; s8[4]=w1.x; s8[5]=w1.y; s8[6]=w1.z; s8[7]=w1.w;
        #pragma unroll
        for (int j = 0; j < 8; j++) a8[j] = bf2f((unsigned short)av[j]);
    } else {
        if (k + 8 <= KK) {
            float4 v0 = *(const float4*)(arowf + k), v1 = *(const float4*)(arowf + k + 4);
            a8[0]=v0.x; a8[1]=v0.y; a8[2]=v0.z; a8[3]=v0.w; a8[4]=v1.x; a8[5]=v1.y; a8[6]=v1.z; a8[7]=v1.w;
            float4 w0 = *(const float4*)(srow + k), w1 = *(const float4*)(srow + k + 4);
            s8[0]=w0.x; s8[1]=w0.y; s8[2]=w0.z; s8[3]=w0.w; s8[4]=w1.x; s8[5]=w1.y; s8[6]=w1.z; s8[7]=w1.w;
        } else {
            #pragma unroll
            for (int j = 0; j < 8; j++){ int kk = k + j; a8[j] = (kk < KK) ? arowf[kk] : 0.f; s8[j] = (kk < KK) ? srow[kk] : 0.f; }
        }
    }
}

// ---------------------------------------------------------------------------
// MFMA scored-GEMM, 2-phase pipelined, A and B both LDS-staged (double-buffered).
// out[m] = sum_c elu( sum_k A[m,k]*S[rowb[m],k] * B[k,c] ) * w[c]
// ---------------------------------------------------------------------------
template<int KK, int BPITCH, int NTILES, bool BFA>
__device__ __forceinline__ void mfma_score_impl(
    const float* __restrict__ Af, const unsigned short* __restrict__ Ab, int lda,
    const unsigned short* __restrict__ Bt,
    const float* __restrict__ S, int sstride, const int* __restrict__ rowb,
    const float* __restrict__ wpad,
    float* __restrict__ out)
{
    __shared__ unsigned short As[2][64*40];
    __shared__ unsigned short Bs[2][304*36];
    __shared__ float red[2][2][32];

    const int t = threadIdx.x;
    const int wave = t >> 6, lane = t & 63;
    const int wr = wave >> 1, wc = wave & 1;
    const int rowBlock = blockIdx.x * 64;

    const int sr = t >> 2;
    const int sk = (t & 3) * 8;
    const int grow = rowBlock + sr;
    const int bb = rowb[grow];
    const float* arowf = nullptr;
    const unsigned short* arowb = nullptr;
    if constexpr (BFA) arowb = Ab + (size_t)grow * lda;
    else               arowf = Af + (size_t)grow * lda;
    const float* srow = S + (size_t)bb * sstride;

    f32x4 acc[2][10];
    #pragma unroll
    for (int rt = 0; rt < 2; rt++)
        #pragma unroll
        for (int ct = 0; ct < 10; ct++) acc[rt][ct] = (f32x4){0.f,0.f,0.f,0.f};

    float a8[8], s8[8];
    s16x8 bvec[5];

    {
        fetch_as<KK, BFA>(arowf, arowb, srow, sk, a8, s8);
        #pragma unroll
        for (int i = 0; i < 5; i++){
            int v = t + 256 * i;
            if (v < 1216) bvec[i] = *(const s16x8*)&Bt[(size_t)(v >> 2) * BPITCH + ((v & 3) * 8)];
        }
        s16x8 pv;
        #pragma unroll
        for (int j = 0; j < 8; j++) pv[j] = (short)f2bf(a8[j] * s8[j]);
        *(s16x8*)&As[0][sr * 40 + sk] = pv;
        #pragma unroll
        for (int i = 0; i < 5; i++){
            int v = t + 256 * i;
            if (v < 1216) *(s16x8*)&Bs[0][(v >> 2) * 36 + ((v & 3) * 8)] = bvec[i];
        }
    }
    __syncthreads();

    int cur = 0;
    for (int kt = 0; kt < NTILES; ++kt) {
        if (kt + 1 < NTILES) {
            fetch_as<KK, BFA>(arowf, arowb, srow, (kt + 1) * 32 + sk, a8, s8);
            int k0 = (kt + 1) * 32;
            #pragma unroll
            for (int i = 0; i < 5; i++){
                int v = t + 256 * i;
                if (v < 1216) bvec[i] = *(const s16x8*)&Bt[(size_t)(v >> 2) * BPITCH + k0 + ((v & 3) * 8)];
            }
        }
        s16x8 af0 = *(s16x8*)&As[cur][(wr * 32 + (lane & 15)) * 40 + (lane >> 4) * 8];
        s16x8 af1 = *(s16x8*)&As[cur][(wr * 32 + 16 + (lane & 15)) * 40 + (lane >> 4) * 8];
        #pragma unroll
        for (int ct = 0; ct < 10; ct++) {
            if (wc == 1 && ct == 9) continue;
            int col = wc * 160 + ct * 16 + (lane & 15);
            s16x8 bf = *(s16x8*)&Bs[cur][col * 36 + (lane >> 4) * 8];
            acc[0][ct] = __builtin_amdgcn_mfma_f32_16x16x32_bf16(af0, bf, acc[0][ct], 0, 0, 0);
            acc[1][ct] = __builtin_amdgcn_mfma_f32_16x16x32_bf16(af1, bf, acc[1][ct], 0, 0, 0);
        }
        if (kt + 1 < NTILES) {
            s16x8 pv;
            #pragma unroll
            for (int j = 0; j < 8; j++) pv[j] = (short)f2bf(a8[j] * s8[j]);
            *(s16x8*)&As[cur ^ 1][sr * 40 + sk] = pv;
            #pragma unroll
            for (int i = 0; i < 5; i++){
                int v = t + 256 * i;
                if (v < 1216) *(s16x8*)&Bs[cur ^ 1][(v >> 2) * 36 + ((v & 3) * 8)] = bvec[i];
            }
        }
        __syncthreads();
        cur ^= 1;
    }

    float p[2][4];
    #pragma unroll
    for (int rt = 0; rt < 2; rt++)
        #pragma unroll
        for (int i = 0; i < 4; i++) p[rt][i] = 0.f;
    #pragma unroll
    for (int ct = 0; ct < 10; ct++) {
        if (wc == 1 && ct == 9) continue;
        int col = wc * 160 + ct * 16 + (lane & 15);
        float wv = wpad[col];
        #pragma unroll
        for (int rt = 0; rt < 2; rt++)
            #pragma unroll
            for (int i = 0; i < 4; i++)
                p[rt][i] += eluf(acc[rt][ct][i]) * wv;
    }
    #pragma unroll
    for (int m = 1; m <= 8; m <<= 1) {
        #pragma unroll
        for (int rt = 0; rt < 2; rt++)
            #pragma unroll
            for (int i = 0; i < 4; i++)
                p[rt][i] += __shfl_xor(p[rt][i], m);
    }
    if ((lane & 15) == 0) {
        int q = lane >> 4;
        #pragma unroll
        for (int rt = 0; rt < 2; rt++)
            #pragma unroll
            for (int i = 0; i < 4; i++)
                red[wr][wc][rt * 16 + q * 4 + i] = p[rt][i];
    }
    __syncthreads();
    if (t < 64) {
        int wrr = t >> 5, r = t & 31;
        out[rowBlock + wrr * 32 + r] = red[wrr][0][r] + red[wrr][1][r];
    }
}

__global__ __launch_bounds__(256, 2) void mfma_node_k(
    const unsigned short* __restrict__ Ab, const unsigned short* __restrict__ Bt,
    const float* __restrict__ S, const int* __restrict__ rowb,
    const float* __restrict__ wpad, float* __restrict__ out)
{
    mfma_score_impl<2400, 2400, 75, true>(nullptr, Ab, 2400, Bt, S, 2400, rowb, wpad, out);
}
__global__ __launch_bounds__(256, 2) void mfma_edge_k(
    const unsigned short* __restrict__ Ab, const unsigned short* __restrict__ Bt,
    const float* __restrict__ S, const int* __restrict__ rowb,
    const float* __restrict__ wpad, float* __restrict__ out)
{
    mfma_score_impl<320, 320, 10, true>(nullptr, Ab, 320, Bt, S, NI * 300, rowb, wpad, out);
}
__global__ __launch_bounds__(256, 2) void mfma_node_f_k(
    const float* __restrict__ A, const unsigned short* __restrict__ Bt,
    const float* __restrict__ S, const int* __restrict__ rowb,
    const float* __restrict__ wpad, float* __restrict__ out)
{
    mfma_score_impl<2400, 2400, 75, false>(A, nullptr, 2400, Bt, S, 2400, rowb, wpad, out);
}
__global__ __launch_bounds__(256, 2) void mfma_edge_f_k(
    const float* __restrict__ A, const unsigned short* __restrict__ Bt,
    const float* __restrict__ S, const int* __restrict__ rowb,
    const float* __restrict__ wpad, float* __restrict__ out)
{
    mfma_score_impl<300, 320, 10, false>(A, nullptr, 300, Bt, S, NI * 300, rowb, wpad, out);
}

// ---------------------------------------------------------------------------
// Generic MFMA GEMM: C[M][ldc] = A[M][K](f32) @ B ; B given as bf16 Bt[col][k]
// padded to 304*gridDim.y cols and bpitch k. Block 256 thr, 64 rows x 304 cols.
// M must be a multiple of 64.
// ---------------------------------------------------------------------------
__global__ __launch_bounds__(256, 2) void mfma_gemm_k(
    const float* __restrict__ A, int lda, int K, int ntiles,
    const unsigned short* __restrict__ Bt, int bpitch,
    int ncols, float* __restrict__ C, int ldc)
{
    __shared__ unsigned short As[2][64*40];
    __shared__ unsigned short Bs[2][304*36];

    const int t = threadIdx.x;
    const int wave = t >> 6, lane = t & 63;
    const int wr = wave >> 1, wc = wave & 1;
    const int rowBlock = blockIdx.x * 64;
    const int colBlock = blockIdx.y * 304;

    const int sr = t >> 2, sk = (t & 3) * 8;
    const float* arow = A + (size_t)(rowBlock + sr) * lda;

    f32x4 acc[2][10];
    #pragma unroll
    for (int rt = 0; rt < 2; rt++)
        #pragma unroll
        for (int ct = 0; ct < 10; ct++) acc[rt][ct] = (f32x4){0.f,0.f,0.f,0.f};

    float a8[8];
    s16x8 bvec[5];

    // prologue
    {
        int k = sk;
        if (k + 8 <= K) {
            float4 v0 = *(const float4*)(arow + k), v1 = *(const float4*)(arow + k + 4);
            a8[0]=v0.x; a8[1]=v0.y; a8[2]=v0.z; a8[3]=v0.w; a8[4]=v1.x; a8[5]=v1.y; a8[6]=v1.z; a8[7]=v1.w;
        } else {
            #pragma unroll
            for (int j = 0; j < 8; j++){ int kk = k + j; a8[j] = (kk < K) ? arow[kk] : 0.f; }
        }
        #pragma unroll
        for (int i = 0; i < 5; i++){
            int v = t + 256 * i;
            if (v < 1216) bvec[i] = *(const s16x8*)&Bt[(size_t)(colBlock + (v >> 2)) * bpitch + ((v & 3) * 8)];
        }
        s16x8 pv;
        #pragma unroll
        for (int j = 0; j < 8; j++) pv[j] = (short)f2bf(a8[j]);
        *(s16x8*)&As[0][sr * 40 + sk] = pv;
        #pragma unroll
        for (int i = 0; i < 5; i++){
            int v = t + 256 * i;
            if (v < 1216) *(s16x8*)&Bs[0][(v >> 2) * 36 + ((v & 3) * 8)] = bvec[i];
        }
    }
    __syncthreads();

    int cur = 0;
    for (int kt = 0; kt < ntiles; ++kt) {
        if (kt + 1 < ntiles) {
            int k = (kt + 1) * 32 + sk;
            if (k + 8 <= K) {
                float4 v0 = *(const float4*)(arow + k), v1 = *(const float4*)(arow + k + 4);
                a8[0]=v0.x; a8[1]=v0.y; a8[2]=v0.z; a8[3]=v0.w; a8[4]=v1.x; a8[5]=v1.y; a8[6]=v1.z; a8[7]=v1.w;
            } else {
                #pragma unroll
                for (int j = 0; j < 8; j++){ int kk = k + j; a8[j] = (kk < K) ? arow[kk] : 0.f; }
            }
            int k0 = (kt + 1) * 32;
            #pragma unroll
            for (int i = 0; i < 5; i++){
                int v = t + 256 * i;
                if (v < 1216) bvec[i] = *(const s16x8*)&Bt[(size_t)(colBlock + (v >> 2)) * bpitch + k0 + ((v & 3) * 8)];
            }
        }
        s16x8 af0 = *(s16x8*)&As[cur][(wr * 32 + (lane & 15)) * 40 + (lane >> 4) * 8];
        s16x8 af1 = *(s16x8*)&As[cur][(wr * 32 + 16 + (lane & 15)) * 40 + (lane >> 4) * 8];
        #pragma unroll
        for (int ct = 0; ct < 10; ct++) {
            if (wc == 1 && ct == 9) continue;
            int col = wc * 160 + ct * 16 + (lane & 15);
            s16x8 bf = *(s16x8*)&Bs[cur][col * 36 + (lane >> 4) * 8];
            acc[0][ct] = __builtin_amdgcn_mfma_f32_16x16x32_bf16(af0, bf, acc[0][ct], 0, 0, 0);
            acc[1][ct] = __builtin_amdgcn_mfma_f32_16x16x32_bf16(af1, bf, acc[1][ct], 0, 0, 0);
        }
        if (kt + 1 < ntiles) {
            s16x8 pv;
            #pragma unroll
            for (int j = 0; j < 8; j++) pv[j] = (short)f2bf(a8[j]);
            *(s16x8*)&As[cur ^ 1][sr * 40 + sk] = pv;
            #pragma unroll
            for (int i = 0; i < 5; i++){
                int v = t + 256 * i;
                if (v < 1216) *(s16x8*)&Bs[cur ^ 1][(v >> 2) * 36 + ((v & 3) * 8)] = bvec[i];
            }
        }
        __syncthreads();
        cur ^= 1;
    }

    // C store: col = lane&15, row = (lane>>4)*4 + i (per 16x16 tile)
    #pragma unroll
    for (int ct = 0; ct < 10; ct++) {
        if (wc == 1 && ct == 9) continue;
        int col = colBlock + wc * 160 + ct * 16 + (lane & 15);
        if (col >= ncols) continue;
        #pragma unroll
        for (int rt = 0; rt < 2; rt++) {
            int row0 = rowBlock + wr * 32 + rt * 16 + (lane >> 4) * 4;
            #pragma unroll
            for (int i = 0; i < 4; i++)
                C[(size_t)(row0 + i) * ldc + col] = acc[rt][ct][i];
        }
    }
}

// ---------------------------------------------------------------------------
// B-table builders (bf16, zero-padded)
// ---------------------------------------------------------------------------
// From (K,N) row-major B: Bt[col][k]
__global__ void build_btg_k(const float* __restrict__ B, int K, int N,
                            int ncpad, int pitch, unsigned short* __restrict__ Bt)
{
    int idx = blockIdx.x * 256 + threadIdx.x;
    if (idx >= ncpad * pitch) return;
    int col = idx / pitch, k = idx - col * pitch;
    float v = (col < N && k < K) ? B[(size_t)k * N + col] : 0.f;
    Bt[idx] = f2bf(v);
}
// From row-major [R][K] matrix used as B^T (cols are rows of src)
__global__ void build_btr_k(const float* __restrict__ Bm, int R, int K,
                            int rpad, int pitch, unsigned short* __restrict__ Bt)
{
    int idx = blockIdx.x * 256 + threadIdx.x;
    if (idx >= rpad * pitch) return;
    int col = idx / pitch, k = idx - col * pitch;
    float v = (col < R && k < K) ? Bm[(size_t)col * K + k] : 0.f;
    Bt[idx] = f2bf(v);
}
// vocab_ext^T: [2128][320]; col<2000 -> cv, col==2000 -> td
__global__ void build_vocab_bt_k(const float* __restrict__ cv, const float* __restrict__ td,
                                 unsigned short* __restrict__ Bt)
{
    int idx = blockIdx.x * 256 + threadIdx.x;
    if (idx >= 2128 * 320) return;
    int col = idx / 320, k = idx - col * 320;
    float v = 0.f;
    if (k < 300) {
        if (col < 2000) v = cv[(size_t)col * 300 + k];
        else if (col == 2000) v = td[k];
    }
    Bt[idx] = f2bf(v);
}

// Convert f32 [rows][K] -> bf16 [rows][pitch], zero-padded.
__global__ void cvt_attr8_k(const float* __restrict__ src, long rows, int K, int pitch,
                            unsigned short* __restrict__ dst)
{
    const int pg = pitch >> 3;
    long total = rows * pg;
    for (long i = (long)blockIdx.x * blockDim.x + threadIdx.x; i < total;
         i += (long)gridDim.x * blockDim.x) {
        long r = i / pg;
        int kg = (int)(i - r * pg) * 8;
        s16x8 v;
        #pragma unroll
        for (int j = 0; j < 8; j++){
            int k = kg + j;
            float x = (k < K) ? src[r * (long)K + k] : 0.f;
            v[j] = (short)f2bf(x);
        }
        *(s16x8*)&dst[r * (long)pitch + kg] = v;
    }
}

__global__ void wpad_k(const float* __restrict__ wn, const float* __restrict__ wr,
                       float* __restrict__ wnp, float* __restrict__ wrp)
{
    int i = threadIdx.x;
    if (i < 304) { wnp[i] = (i < 300) ? wn[i] : 0.f; wrp[i] = (i < 300) ? wr[i] : 0.f; }
}

template<int EPI>
__global__ void mm_naive_bt_k(const float* __restrict__ A, int lda, int M, int K,
                              const float* __restrict__ Bm, int N,
                              const float* __restrict__ bias,
                              float* __restrict__ Cf)
{
    int idx = blockIdx.x * 256 + threadIdx.x;
    if (idx >= M * N) return;
    int m = idx / N;
    int j = idx - m * N;
    const float* arow = A + (size_t)m * lda;
    const float* brow = Bm + (size_t)j * K;
    float s = 0.f;
    for (int k = 0; k < K; k++) s += arow[k] * brow[k];
    if (EPI == 0) Cf[idx] = s;
    else if (EPI == 2) Cf[idx] = eluf(s + bias[j]);
    else Cf[idx] = s + bias[j];
}

__global__ void transpose_k(const float* __restrict__ src, int R, int C,
                            float* __restrict__ dst)
{
    int idx = blockIdx.x * 256 + threadIdx.x;
    if (idx >= R * C) return;
    int r = idx / C, c = idx - r * C;
    dst[(size_t)c * R + r] = src[idx];
}

// Pack lstm Whh [1200][300] -> bf16 k-major WT[k][1200]
__global__ void pack_whhT_k(const float* __restrict__ W, unsigned short* __restrict__ WT)
{
    int idx = blockIdx.x * 256 + threadIdx.x;
    if (idx >= 300 * 1200) return;
    int k = idx / 1200, r = idx - k * 1200;
    WT[idx] = f2bf(W[(size_t)r * 300 + k]);
}

// ---------------------------------------------------------------------------
__global__ void softmax_rows_k(float* __restrict__ X, int nc)
{
    int row = blockIdx.x, t = threadIdx.x;
    __shared__ float red[256];
    size_t base = (size_t)row * nc;
    float m = -3.4e38f;
    for (int i = t; i < nc; i += 256) m = fmaxf(m, X[base + i]);
    red[t] = m; __syncthreads();
    for (int s = 128; s > 0; s >>= 1){ if (t < s) red[t] = fmaxf(red[t], red[t+s]); __syncthreads(); }
    float mx = red[0]; __syncthreads();
    float sm = 0.f;
    for (int i = t; i < nc; i += 256){ float e = expf(X[base + i] - mx); X[base + i] = e; sm += e; }
    red[t] = sm; __syncthreads();
    for (int s = 128; s > 0; s >>= 1){ if (t < s) red[t] += red[t+s]; __syncthreads(); }
    float inv = 1.f / red[0];
    for (int i = t; i < nc; i += 256) X[base + i] *= inv;
}

__global__ void tagged_add_k(const float* __restrict__ sim, const float* __restrict__ q,
                             float* __restrict__ tg)
{
    int idx = blockIdx.x * 256 + threadIdx.x;
    if (idx >= 960 * 300) return;
    int row = idx / 300;
    tg[idx] += sim[(size_t)row * 2001 + 2000] * q[idx];
}

// Fast persistent LSTM (round-5 measured-good version): 1 block/batch, 640 thr.
// Threads 0..599 each own 2 gate rows; threads 0..299 own hid t.
__global__ __launch_bounds__(640) void lstm_fast_k(
    const float* __restrict__ xW, const unsigned short* __restrict__ WT,
    const float* __restrict__ bih, const float* __restrict__ bhh,
    const int* __restrict__ lengths, float* __restrict__ encoded)
{
    __shared__ float hs[300];
    __shared__ float gs[1200];
    const int b = blockIdx.x, t = threadIdx.x;
    const int len = lengths[b];
    const bool ga = t < 600;
    const bool ha = t < 300;
    float bs0 = 0.f, bs1 = 0.f;
    if (ga) { bs0 = bih[2*t] + bhh[2*t]; bs1 = bih[2*t+1] + bhh[2*t+1]; }
    if (ha) hs[t] = 0.f;
    float c = 0.f, h = 0.f;
    __syncthreads();
    const float* xb = xW + (size_t)b * Ll * 1200;
    for (int st = 0; st < len; ++st) {
        if (ga) {
            float d0 = 0.f, d1 = 0.f;
            const unsigned short* wp = WT + 2 * t;
            #pragma unroll 4
            for (int k = 0; k < 300; k++) {
                float hk = hs[k];
                unsigned wv = *(const unsigned*)(wp + (size_t)k * 1200);
                d0 = fmaf(hk, __uint_as_float(wv << 16), d0);
                d1 = fmaf(hk, __uint_as_float(wv & 0xFFFF0000u), d1);
            }
            const float* xr = xb + st * 1200;
            gs[2*t]   = xr[2*t]   + bs0 + d0;
            gs[2*t+1] = xr[2*t+1] + bs1 + d1;
        }
        __syncthreads();
        if (ha) {
            float i_ = sigf(gs[t]);
            float f_ = sigf(gs[300 + t]);
            float g_ = tanhf(gs[600 + t]);
            float o_ = sigf(gs[900 + t]);
            c = f_ * c + i_ * g_;
            h = o_ * tanhf(c);
            hs[t] = h;
        }
        __syncthreads();
    }
    if (ha) encoded[b * 300 + t] = h;
}

// Persistent RNN decoder
__global__ __launch_bounds__(320) void rnn_all_k(
    const float* __restrict__ enc, const float* __restrict__ WihT,
    const float* __restrict__ WhhT,
    const float* __restrict__ bih, const float* __restrict__ bhh,
    float* __restrict__ hidden)
{
    __shared__ float es[304];
    __shared__ float hs[304];
    const int b = blockIdx.x, i = threadIdx.x;
    const bool act = i < 300;
    if (act) { es[i] = enc[b * 300 + i]; hs[i] = 0.f; }
    __syncthreads();
    float ex = 0.f;
    if (act) {
        #pragma unroll 8
        for (int k = 0; k < 300; k++)
            ex = fmaf(es[k], WihT[(size_t)k * 300 + i], ex);
        ex += bih[i] + bhh[i];
    }
    for (int it = 0; it < NI; it++) {
        __syncthreads();
        float d = 0.f;
        if (act) {
            #pragma unroll 8
            for (int k = 0; k < 300; k++)
                d = fmaf(hs[k], WhhT[(size_t)k * 300 + i], d);
        }
        float v = fmaxf(ex + d, 0.f);
        __syncthreads();
        if (act) { hs[i] = v; hidden[((size_t)b * NI + it) * 300 + i] = v; }
    }
}

__global__ __launch_bounds__(256) void scores_instr_k(
    const float* __restrict__ hidden, const float* __restrict__ tagged,
    const int* __restrict__ lengths, float* __restrict__ instr)
{
    __shared__ float sc[4][32];
    int wv = threadIdx.x >> 6;
    int wid = blockIdx.x * 4 + wv;
    int lane = threadIdx.x & 63;
    int b = wid / NI;
    const float* hr = hidden + (size_t)wid * Hh;
    float hv[5];
    #pragma unroll
    for (int p = 0; p < 5; p++){ int k = lane + p * 64; hv[p] = (k < Hh) ? hr[k] : 0.f; }
    int len = lengths[b];
    for (int l = 0; l < Ll; l++){
        const float* trw = tagged + ((size_t)b * Ll + l) * Hh;
        float s = 0.f;
        #pragma unroll
        for (int p = 0; p < 5; p++){ int k = lane + p * 64; if (k < Hh) s += hv[p] * trw[k]; }
        s = wave_sum(s);
        if (lane == 0) sc[wv][l] = s;
    }
    __syncthreads();
    float mx = -3.4e38f;
    for (int l = 0; l < len; l++) mx = fmaxf(mx, sc[wv][l]);
    float sum = 0.f;
    for (int l = 0; l < len; l++) sum += expf(sc[wv][l] - mx);
    float inv = 1.f / sum;
    float a[5] = {0.f,0.f,0.f,0.f,0.f};
    for (int l = 0; l < len; l++){
        float pl = expf(sc[wv][l] - mx) * inv;
        const float* trw = tagged + ((size_t)b * Ll + l) * Hh;
        #pragma unroll
        for (int p = 0; p < 5; p++){ int k = lane + p * 64; if (k < Hh) a[p] += pl * trw[k]; }
    }
    #pragma unroll
    for (int p = 0; p < 5; p++){ int k = lane + p * 64; if (k < Hh) instr[(size_t)wid * Hh + k] = a[p]; }
}

__global__ __launch_bounds__(256) void prop_softmax_k(
    const float* __restrict__ instr, int ii, const float* __restrict__ pemb,
    float* __restrict__ psim, float* __restrict__ rsim)
{
    int wid = blockIdx.x * 4 + (threadIdx.x >> 6);
    int lane = threadIdx.x & 63;
    const float* ir = instr + ((size_t)wid * NI + ii) * Hh;
    float iv[5];
    #pragma unroll
    for (int p = 0; p < 5; p++){ int k = lane + p * 64; iv[p] = (k < Hh) ? ir[k] : 0.f; }
    float e[9];
    #pragma unroll
    for (int j = 0; j < 9; j++){
        const float* pr = pemb + j * Hh;
        float s = 0.f;
        #pragma unroll
        for (int p = 0; p < 5; p++){ int k = lane + p * 64; if (k < Hh) s += iv[p] * pr[k]; }
        e[j] = wave_sum(s);
    }
    if (lane == 0){
        float mx = e[0];
        #pragma unroll
        for (int j = 1; j < 9; j++) mx = fmaxf(mx, e[j]);
        float sum = 0.f;
        #pragma unroll
        for (int j = 0; j < 9; j++){ e[j] = expf(e[j] - mx); sum += e[j]; }
        float inv = 1.f / sum;
        #pragma unroll
        for (int p = 0; p < 8; p++) psim[wid * 8 + p] = e[p] * inv;
        rsim[wid] = e[8] * inv;
    }
}

__global__ void iscale_k(const float* __restrict__ instr, int step,
                         const float* __restrict__ psim, float* __restrict__ iscale)
{
    int idx = blockIdx.x * 256 + threadIdx.x;
    if (idx >= Bb * 2400) return;
    int b = idx / 2400; int k = idx - b * 2400;
    int p = k / 300;    int h = k - p * 300;
    iscale[idx] = instr[((size_t)b * NI + step) * Hh + h] * psim[b * 8 + p];
}

__global__ void count_k(const int* __restrict__ ni, int* __restrict__ cnt)
{
    int n = blockIdx.x * 256 + threadIdx.x;
    if (n < Nn) atomicAdd(&cnt[ni[n]], 1);
}
__global__ void dist_init_k(const int* __restrict__ ni, const int* __restrict__ cnt,
                            float* __restrict__ dist)
{
    int n = blockIdx.x * 256 + threadIdx.x;
    if (n < Nn) dist[n] = 1.f / (float)cnt[ni[n]];
}

__global__ void edge_msg_k(const int* __restrict__ ei, const float* __restrict__ es,
                           const float* __restrict__ dist, float* __restrict__ msgdot)
{
    int e = blockIdx.x * 256 + threadIdx.x;
    if (e < Ee){
        int s = ei[e];
        int d = ei[Ee + e];
        atomicAdd(&msgdot[d], dist[s] * es[e]);
    }
}

__global__ __launch_bounds__(256) void seg_update_k(
    const float* __restrict__ nscore, const float* __restrict__ msgdot,
    const float* __restrict__ rsim, float* __restrict__ dist)
{
    int b = blockIdx.x, t = threadIdx.x;
    __shared__ float red[256];
    int n0 = b * NPG;
    float a1 = nscore[n0 + t], a2 = nscore[n0 + 256 + t];
    float m1 = msgdot[n0 + t], m2 = msgdot[n0 + 256 + t];

    red[t] = fmaxf(a1, a2); __syncthreads();
    for (int s = 128; s > 0; s >>= 1){ if (t < s) red[t] = fmaxf(red[t], red[t+s]); __syncthreads(); }
    float mN = red[0]; __syncthreads();
    float e1 = expf(a1 - mN), e2 = expf(a2 - mN);
    red[t] = e1 + e2; __syncthreads();
    for (int s = 128; s > 0; s >>= 1){ if (t < s) red[t] += red[t+s]; __syncthreads(); }
    float sN = red[0]; __syncthreads();

    red[t] = fmaxf(m1, m2); __syncthreads();
    for (int s = 128; s > 0; s >>= 1){ if (t < s) red[t] = fmaxf(red[t], red[t+s]); __syncthreads(); }
    float mM = red[0]; __syncthreads();
    float f1 = expf(m1 - mM), f2 = expf(m2 - mM);
    red[t] = f1 + f2; __syncthreads();
    for (int s = 128; s > 0; s >>= 1){ if (t < s) red[t] += red[t+s]; __syncthreads(); }
    float sM = red[0];

    float rs = rsim[b];
    dist[n0 + t]       = rs * (f1 / sM) + (1.f - rs) * (e1 / sN);
    dist[n0 + 256 + t] = rs * (f2 / sM) + (1.f - rs) * (e2 / sN);
}

__global__ __launch_bounds__(320) void final_agg_k(
    const float* __restrict__ psim, const float* __restrict__ dist,
    const float* __restrict__ na, float* __restrict__ agg)
{
    int chunk = blockIdx.x;
    int b = blockIdx.y;
    int h = threadIdx.x;
    if (h >= Hh) return;
    float ps[8];
    #pragma unroll
    for (int p = 0; p < 8; p++) ps[p] = psim[b * 8 + p];
    float acc = 0.f;
    for (int i = 0; i < 32; i++){
        int n = b * NPG + chunk * 32 + i;
        const float* row = na + (size_t)n * Pp * Hh;
        float wsum = 0.f;
        #pragma unroll
        for (int p = 0; p < 8; p++) wsum += ps[p] * row[p * Hh + h];
        acc += dist[n] * wsum;
    }
    atomicAdd(&agg[b * Hh + h], acc);
}

__global__ void feats_k(const float* __restrict__ enc, const float* __restrict__ agg,
                        float* __restrict__ feats)
{
    int idx = blockIdx.x * 256 + threadIdx.x;
    if (idx >= Bb * 600) return;
    int b = idx / 600, j = idx - b * 600;
    feats[idx] = (j < 300) ? enc[b * 300 + j] : agg[b * 300 + (j - 300)];
}

// ---------------------------------------------------------------------------
extern "C" void kernel_launch(void* const* d_in, const int* in_sizes, int n_in,
                              void* d_out, int out_size, void* d_ws, size_t ws_size,
                              hipStream_t stream)
{
    const float* questions      = (const float*)d_in[0];
    const int*   lengths        = (const int*)  d_in[1];
    const int*   node_indices   = (const int*)  d_in[2];
    const int*   edge_indices   = (const int*)  d_in[3];
    const int*   edge_batch     = (const int*)  d_in[4];
    const float* node_attrs     = (const float*)d_in[5];
    const float* edge_attrs     = (const float*)d_in[6];
    const float* concept_vocab  = (const float*)d_in[7];
    const float* prop_emb       = (const float*)d_in[8];
    const float* tagger_default = (const float*)d_in[9];
    const float* tagger_weight  = (const float*)d_in[10];
    const float* lstm_Wih       = (const float*)d_in[11];
    const float* lstm_Whh       = (const float*)d_in[12];
    const float* lstm_bih       = (const float*)d_in[13];
    const float* lstm_bhh       = (const float*)d_in[14];
    const float* rnn_Wih        = (const float*)d_in[15];
    const float* rnn_Whh        = (const float*)d_in[16];
    const float* rnn_bih        = (const float*)d_in[17];
    const float* rnn_bhh        = (const float*)d_in[18];
    const float* Wnp            = (const float*)d_in[19];
    const float* Wedge          = (const float*)d_in[20];
    const float* w_nscore       = (const float*)d_in[21];
    const float* w_rscore       = (const float*)d_in[22];
    const float* fc1_W          = (const float*)d_in[23];
    const float* fc1_b          = (const float*)d_in[24];
    const float* fc2_W          = (const float*)d_in[25];
    const float* fc2_b          = (const float*)d_in[26];
    float* outf = (float*)d_out;

    float* ws = (float*)d_ws;
    size_t off = 0;
    auto alloc = [&](size_t n){ size_t r = off; off += (n + 63) & ~(size_t)63; return r; };
    size_t o_q2     = alloc(960 * 300);
    size_t o_sim    = alloc((size_t)960 * 2001);
    size_t o_tagged = alloc(960 * 300);
    size_t o_xw     = alloc((size_t)960 * 1200);
    size_t o_enc    = alloc(9600);
    size_t o_hidden = alloc(48000);
    size_t o_instr  = alloc(48000);
    size_t o_psim   = alloc(256);
    size_t o_rsim   = alloc(64);
    size_t o_iscale = alloc((size_t)Bb * 2400);
    size_t o_nscore = alloc(Nn);
    size_t o_es     = alloc(Ee);
    size_t o_msgdot = alloc(Nn);
    size_t o_dist   = alloc(Nn);
    size_t o_cnt    = alloc(64);
    size_t o_agg    = alloc(9600);
    size_t o_feats  = alloc(19200);
    size_t o_z      = alloc(19200);
    size_t o_btn    = alloc((size_t)304 * 2400 / 2);   // Wnp^T bf16
    size_t o_bte    = alloc((size_t)304 * 320 / 2);    // Wedge^T bf16
    size_t o_wn     = alloc(304);
    size_t o_wr     = alloc(304);
    size_t o_wlstm  = alloc(180000);                   // lstm Whh bf16 [300][1200]
    size_t o_rwhhT  = alloc(90000);
    size_t o_rwihT  = alloc(90000);
    // tagger-chain bf16 B tables
    size_t o_btq    = alloc((size_t)304 * 320 / 2);    // tagger_weight^T
    size_t o_btv    = alloc((size_t)2128 * 320 / 2);   // vocab_ext^T
    size_t o_btc    = alloc((size_t)304 * 2016 / 2);   // concept_vocab^T
    size_t o_btw    = alloc((size_t)1216 * 320 / 2);   // lstm_Wih (as B^T)
    // big bf16 attr copies (gated on ws_size)
    size_t o_nab    = alloc((size_t)Nn * 2400 / 2);
    size_t o_eab    = alloc((size_t)Ee * 320 / 2);
    const bool bigws = ws_size >= off * sizeof(float);

    unsigned short* btn = (unsigned short*)(ws + o_btn);
    unsigned short* bte = (unsigned short*)(ws + o_bte);
    unsigned short* wlstm = (unsigned short*)(ws + o_wlstm);
    unsigned short* btq = (unsigned short*)(ws + o_btq);
    unsigned short* btv = (unsigned short*)(ws + o_btv);
    unsigned short* btc = (unsigned short*)(ws + o_btc);
    unsigned short* btw = (unsigned short*)(ws + o_btw);
    unsigned short* nab = (unsigned short*)(ws + o_nab);
    unsigned short* eab = (unsigned short*)(ws + o_eab);

    // ---- one-time conversions ----
    build_btg_k<<<(304*2400 + 255)/256, 256, 0, stream>>>(Wnp, 2400, 300, 304, 2400, btn);
    build_btg_k<<<(304*320 + 255)/256, 256, 0, stream>>>(Wedge, 300, 300, 304, 320, bte);
    wpad_k<<<1, 320, 0, stream>>>(w_nscore, w_rscore, ws + o_wn, ws + o_wr);
    pack_whhT_k<<<(300*1200 + 255)/256, 256, 0, stream>>>(lstm_Whh, wlstm);
    transpose_k<<<(300*300 + 255)/256, 256, 0, stream>>>(rnn_Whh, 300, 300, ws + o_rwhhT);
    transpose_k<<<(300*300 + 255)/256, 256, 0, stream>>>(rnn_Wih, 300, 300, ws + o_rwihT);
    build_btg_k<<<(304*320 + 255)/256, 256, 0, stream>>>(tagger_weight, 300, 300, 304, 320, btq);
    build_vocab_bt_k<<<(2128*320 + 255)/256, 256, 0, stream>>>(concept_vocab, tagger_default, btv);
    build_btg_k<<<(304*2016 + 255)/256, 256, 0, stream>>>(concept_vocab, 2000, 300, 304, 2016, btc);
    build_btr_k<<<(1216*320 + 255)/256, 256, 0, stream>>>(lstm_Wih, 1200, 300, 1216, 320, btw);
    if (bigws) {
        cvt_attr8_k<<<2048, 256, 0, stream>>>(node_attrs, Nn, 2400, 2400, nab);
        cvt_attr8_k<<<2048, 256, 0, stream>>>(edge_attrs, Ee, 300, 320, eab);
    }

    // ---- tagger chain (all MFMA) ----
    // q2 = questions @ tagger_weight
    mfma_gemm_k<<<dim3(15,1), 256, 0, stream>>>(
        questions, 300, 300, 10, btq, 320, 300, ws + o_q2, 300);
    // logits = q2 @ vocab_ext^T
    mfma_gemm_k<<<dim3(15,7), 256, 0, stream>>>(
        ws + o_q2, 300, 300, 10, btv, 320, 2001, ws + o_sim, 2001);
    softmax_rows_k<<<960, 256, 0, stream>>>(ws + o_sim, 2001);
    // tagged = sim[:, :2000] @ concept_vocab
    mfma_gemm_k<<<dim3(15,1), 256, 0, stream>>>(
        ws + o_sim, 2001, 2000, 63, btc, 2016, 300, ws + o_tagged, 300);
    tagged_add_k<<<1125, 256, 0, stream>>>(ws + o_sim, questions, ws + o_tagged);

    // ---- LSTM ----
    // xW = tagged @ lstm_Wih^T
    mfma_gemm_k<<<dim3(15,4), 256, 0, stream>>>(
        ws + o_tagged, 300, 300, 10, btw, 320, 1200, ws + o_xw, 1200);
    lstm_fast_k<<<Bb, 640, 0, stream>>>(ws + o_xw, wlstm, lstm_bih, lstm_bhh,
                                        lengths, ws + o_enc);

    // ---- RNN instruction decoder + instructions ----
    rnn_all_k<<<Bb, 320, 0, stream>>>(ws + o_enc, ws + o_rwihT, ws + o_rwhhT,
                                      rnn_bih, rnn_bhh, ws + o_hidden);
    scores_instr_k<<<40, 256, 0, stream>>>(ws + o_hidden, ws + o_tagged, lengths, ws + o_instr);

    // ---- distribution init ----
    hipMemsetAsync(ws + o_cnt, 0, 32 * sizeof(int), stream);
    count_k<<<64, 256, 0, stream>>>(node_indices, (int*)(ws + o_cnt));
    dist_init_k<<<64, 256, 0, stream>>>(node_indices, (int*)(ws + o_cnt), ws + o_dist);

    // ---- 4 message-passing steps ----
    for (int step = 0; step < 4; step++){
        prop_softmax_k<<<8, 256, 0, stream>>>(ws + o_instr, step, prop_emb, ws + o_psim, ws + o_rsim);
        iscale_k<<<300, 256, 0, stream>>>(ws + o_instr, step, ws + o_psim, ws + o_iscale);
        if (bigws) {
            mfma_node_k<<<Nn/64, 256, 0, stream>>>(
                nab, btn, ws + o_iscale, node_indices, ws + o_wn, ws + o_nscore);
            mfma_edge_k<<<Ee/64, 256, 0, stream>>>(
                eab, bte, ws + o_instr + step * 300, edge_batch, ws + o_wr, ws + o_es);
        } else {
            mfma_node_f_k<<<Nn/64, 256, 0, stream>>>(
                node_attrs, btn, ws + o_iscale, node_indices, ws + o_wn, ws + o_nscore);
            mfma_edge_f_k<<<Ee/64, 256, 0, stream>>>(
                edge_attrs, bte, ws + o_instr + step * 300, edge_batch, ws + o_wr, ws + o_es);
        }
        hipMemsetAsync(ws + o_msgdot, 0, Nn * sizeof(float), stream);
        edge_msg_k<<<512, 256, 0, stream>>>(edge_indices, ws + o_es, ws + o_dist, ws + o_msgdot);
        seg_update_k<<<32, 256, 0, stream>>>(ws + o_nscore, ws + o_msgdot, ws + o_rsim, ws + o_dist);
    }

    // ---- final aggregation + FCs ----
    prop_softmax_k<<<8, 256, 0, stream>>>(ws + o_instr, 4, prop_emb, ws + o_psim, ws + o_rsim);
    hipMemsetAsync(ws + o_agg, 0, 9600 * sizeof(float), stream);
    final_agg_k<<<dim3(16,32), 320, 0, stream>>>(ws + o_psim, ws + o_dist, node_attrs, ws + o_agg);
    feats_k<<<75, 256, 0, stream>>>(ws + o_enc, ws + o_agg, ws + o_feats);
    mm_naive_bt_k<2><<<75, 256, 0, stream>>>(
        ws + o_feats, 600, 32, 600, fc1_W, 600, fc1_b, ws + o_z);
    mm_naive_bt_k<3><<<(32*1845 + 255)/256, 256, 0, stream>>>(
        ws + o_z, 600, 32, 600, fc2_W, 1845, fc2_b, outf);
}

// Round 8
// 1830.568 us; speedup vs baseline: 2.9264x; 1.0648x over previous
//
#include <hip/hip_runtime.h>
#include <hip/hip_bf16.h>
#include <math.h>

// Problem constants (fixed by setup_inputs)
#define Bb   32
#define Ll   30
#define Hh   300
#define Pp   8
#define Nn   16384
#define Ee   131072
#define NPG  512
#define NI   5

typedef __attribute__((ext_vector_type(4))) float f32x4;
typedef __attribute__((ext_vector_type(8))) short s16x8;

__device__ __forceinline__ float eluf(float x){ return x > 0.f ? x : expm1f(x); }
__device__ __forceinline__ float sigf(float x){ return 1.f/(1.f+expf(-x)); }
__device__ __forceinline__ float wave_sum(float s){
    s += __shfl_xor(s, 32); s += __shfl_xor(s, 16); s += __shfl_xor(s, 8);
    s += __shfl_xor(s, 4);  s += __shfl_xor(s, 2);  s += __shfl_xor(s, 1);
    return s;
}
__device__ __forceinline__ unsigned short f2bf(float x){
    unsigned u = __float_as_uint(x);
    unsigned r = u + 0x7FFFu + ((u >> 16) & 1u);
    return (unsigned short)(r >> 16);
}
__device__ __forceinline__ float bf2f(unsigned short v){
    return __uint_as_float(((unsigned)v) << 16);
}

// ---------------------------------------------------------------------------
// A-tile fetch: fills a8 (A values as f32) and s8 (scale values).
// ---------------------------------------------------------------------------
template<int KK, bool BFA>
__device__ __forceinline__ void fetch_as(const float* __restrict__ arowf,
                                         const unsigned short* __restrict__ arowb,
                                         const float* __restrict__ srow,
                                         int k, float* a8, float* s8)
{
    if constexpr (BFA) {
        s16x8 av = *(const s16x8*)(arowb + k);
        float4 w0 = *(const float4*)(srow + k), w1 = *(const float4*)(srow + k + 4);
        s8[0]=w0.x; s8[1]=w0.y; s8[2]=w0.z; s8[3]=w0.w; s8[4]=w1.x; s8[5]=w1.y; s8[6]=w1.z; s8[7]=w1.w;
        #pragma unroll
        for (int j = 0; j < 8; j++) a8[j] = bf2f((unsigned short)av[j]);
    } else {
        if (k + 8 <= KK) {
            float4 v0 = *(const float4*)(arowf + k), v1 = *(const float4*)(arowf + k + 4);
            a8[0]=v0.x; a8[1]=v0.y; a8[2]=v0.z; a8[3]=v0.w; a8[4]=v1.x; a8[5]=v1.y; a8[6]=v1.z; a8[7]=v1.w;
            float4 w0 = *(const float4*)(srow + k), w1 = *(const float4*)(srow + k + 4);
            s8[0]=w0.x; s8[1]=w0.y; s8[2]=w0.z; s8[3]=w0.w; s8[4]=w1.x; s8[5]=w1.y; s8[6]=w1.z; s8[7]=w1.w;
        } else {
            #pragma unroll
            for (int j = 0; j < 8; j++){ int kk = k + j; a8[j] = (kk < KK) ? arowf[kk] : 0.f; s8[j] = (kk < KK) ? srow[kk] : 0.f; }
        }
    }
}

// ---------------------------------------------------------------------------
// MFMA scored-GEMM, 2-phase pipelined, A and B both LDS-staged (double-buffered).
// out[m] = sum_c elu( sum_k A[m,k]*S[rowb[m],k] * B[k,c] ) * w[c]
// ---------------------------------------------------------------------------
template<int KK, int BPITCH, int NTILES, bool BFA>
__device__ __forceinline__ void mfma_score_impl(
    const float* __restrict__ Af, const unsigned short* __restrict__ Ab, int lda,
    const unsigned short* __restrict__ Bt,
    const float* __restrict__ S, int sstride, const int* __restrict__ rowb,
    const float* __restrict__ wpad,
    float* __restrict__ out)
{
    __shared__ unsigned short As[2][64*40];
    __shared__ unsigned short Bs[2][304*36];
    __shared__ float red[2][2][32];

    const int t = threadIdx.x;
    const int wave = t >> 6, lane = t & 63;
    const int wr = wave >> 1, wc = wave & 1;
    const int rowBlock = blockIdx.x * 64;

    const int sr = t >> 2;
    const int sk = (t & 3) * 8;
    const int grow = rowBlock + sr;
    const int bb = rowb[grow];
    const float* arowf = nullptr;
    const unsigned short* arowb = nullptr;
    if constexpr (BFA) arowb = Ab + (size_t)grow * lda;
    else               arowf = Af + (size_t)grow * lda;
    const float* srow = S + (size_t)bb * sstride;

    f32x4 acc[2][10];
    #pragma unroll
    for (int rt = 0; rt < 2; rt++)
        #pragma unroll
        for (int ct = 0; ct < 10; ct++) acc[rt][ct] = (f32x4){0.f,0.f,0.f,0.f};

    float a8[8], s8[8];
    s16x8 bvec[5];

    {
        fetch_as<KK, BFA>(arowf, arowb, srow, sk, a8, s8);
        #pragma unroll
        for (int i = 0; i < 5; i++){
            int v = t + 256 * i;
            if (v < 1216) bvec[i] = *(const s16x8*)&Bt[(size_t)(v >> 2) * BPITCH + ((v & 3) * 8)];
        }
        s16x8 pv;
        #pragma unroll
        for (int j = 0; j < 8; j++) pv[j] = (short)f2bf(a8[j] * s8[j]);
        *(s16x8*)&As[0][sr * 40 + sk] = pv;
        #pragma unroll
        for (int i = 0; i < 5; i++){
            int v = t + 256 * i;
            if (v < 1216) *(s16x8*)&Bs[0][(v >> 2) * 36 + ((v & 3) * 8)] = bvec[i];
        }
    }
    __syncthreads();

    int cur = 0;
    for (int kt = 0; kt < NTILES; ++kt) {
        if (kt + 1 < NTILES) {
            fetch_as<KK, BFA>(arowf, arowb, srow, (kt + 1) * 32 + sk, a8, s8);
            int k0 = (kt + 1) * 32;
            #pragma unroll
            for (int i = 0; i < 5; i++){
                int v = t + 256 * i;
                if (v < 1216) bvec[i] = *(const s16x8*)&Bt[(size_t)(v >> 2) * BPITCH + k0 + ((v & 3) * 8)];
            }
        }
        s16x8 af0 = *(s16x8*)&As[cur][(wr * 32 + (lane & 15)) * 40 + (lane >> 4) * 8];
        s16x8 af1 = *(s16x8*)&As[cur][(wr * 32 + 16 + (lane & 15)) * 40 + (lane >> 4) * 8];
        #pragma unroll
        for (int ct = 0; ct < 10; ct++) {
            if (wc == 1 && ct == 9) continue;
            int col = wc * 160 + ct * 16 + (lane & 15);
            s16x8 bf = *(s16x8*)&Bs[cur][col * 36 + (lane >> 4) * 8];
            acc[0][ct] = __builtin_amdgcn_mfma_f32_16x16x32_bf16(af0, bf, acc[0][ct], 0, 0, 0);
            acc[1][ct] = __builtin_amdgcn_mfma_f32_16x16x32_bf16(af1, bf, acc[1][ct], 0, 0, 0);
        }
        if (kt + 1 < NTILES) {
            s16x8 pv;
            #pragma unroll
            for (int j = 0; j < 8; j++) pv[j] = (short)f2bf(a8[j] * s8[j]);
            *(s16x8*)&As[cur ^ 1][sr * 40 + sk] = pv;
            #pragma unroll
            for (int i = 0; i < 5; i++){
                int v = t + 256 * i;
                if (v < 1216) *(s16x8*)&Bs[cur ^ 1][(v >> 2) * 36 + ((v & 3) * 8)] = bvec[i];
            }
        }
        __syncthreads();
        cur ^= 1;
    }

    float p[2][4];
    #pragma unroll
    for (int rt = 0; rt < 2; rt++)
        #pragma unroll
        for (int i = 0; i < 4; i++) p[rt][i] = 0.f;
    #pragma unroll
    for (int ct = 0; ct < 10; ct++) {
        if (wc == 1 && ct == 9) continue;
        int col = wc * 160 + ct * 16 + (lane & 15);
        float wv = wpad[col];
        #pragma unroll
        for (int rt = 0; rt < 2; rt++)
            #pragma unroll
            for (int i = 0; i < 4; i++)
                p[rt][i] += eluf(acc[rt][ct][i]) * wv;
    }
    #pragma unroll
    for (int m = 1; m <= 8; m <<= 1) {
        #pragma unroll
        for (int rt = 0; rt < 2; rt++)
            #pragma unroll
            for (int i = 0; i < 4; i++)
                p[rt][i] += __shfl_xor(p[rt][i], m);
    }
    if ((lane & 15) == 0) {
        int q = lane >> 4;
        #pragma unroll
        for (int rt = 0; rt < 2; rt++)
            #pragma unroll
            for (int i = 0; i < 4; i++)
                red[wr][wc][rt * 16 + q * 4 + i] = p[rt][i];
    }
    __syncthreads();
    if (t < 64) {
        int wrr = t >> 5, r = t & 31;
        out[rowBlock + wrr * 32 + r] = red[wrr][0][r] + red[wrr][1][r];
    }
}

__global__ __launch_bounds__(256, 2) void mfma_node_k(
    const unsigned short* __restrict__ Ab, const unsigned short* __restrict__ Bt,
    const float* __restrict__ S, const int* __restrict__ rowb,
    const float* __restrict__ wpad, float* __restrict__ out)
{
    mfma_score_impl<2400, 2400, 75, true>(nullptr, Ab, 2400, Bt, S, 2400, rowb, wpad, out);
}
__global__ __launch_bounds__(256, 2) void mfma_edge_k(
    const unsigned short* __restrict__ Ab, const unsigned short* __restrict__ Bt,
    const float* __restrict__ S, const int* __restrict__ rowb,
    const float* __restrict__ wpad, float* __restrict__ out)
{
    mfma_score_impl<320, 320, 10, true>(nullptr, Ab, 320, Bt, S, NI * 300, rowb, wpad, out);
}
__global__ __launch_bounds__(256, 2) void mfma_node_f_k(
    const float* __restrict__ A, const unsigned short* __restrict__ Bt,
    const float* __restrict__ S, const int* __restrict__ rowb,
    const float* __restrict__ wpad, float* __restrict__ out)
{
    mfma_score_impl<2400, 2400, 75, false>(A, nullptr, 2400, Bt, S, 2400, rowb, wpad, out);
}
__global__ __launch_bounds__(256, 2) void mfma_edge_f_k(
    const float* __restrict__ A, const unsigned short* __restrict__ Bt,
    const float* __restrict__ S, const int* __restrict__ rowb,
    const float* __restrict__ wpad, float* __restrict__ out)
{
    mfma_score_impl<300, 320, 10, false>(A, nullptr, 300, Bt, S, NI * 300, rowb, wpad, out);
}

// ---------------------------------------------------------------------------
// Generic MFMA GEMM (tagger chain): C = A(f32) @ B with bf16 Bt[col][k].
// ---------------------------------------------------------------------------
__global__ __launch_bounds__(256, 2) void mfma_gemm_k(
    const float* __restrict__ A, int lda, int K, int ntiles,
    const unsigned short* __restrict__ Bt, int bpitch,
    int ncols, float* __restrict__ C, int ldc)
{
    __shared__ unsigned short As[2][64*40];
    __shared__ unsigned short Bs[2][304*36];

    const int t = threadIdx.x;
    const int wave = t >> 6, lane = t & 63;
    const int wr = wave >> 1, wc = wave & 1;
    const int rowBlock = blockIdx.x * 64;
    const int colBlock = blockIdx.y * 304;

    const int sr = t >> 2, sk = (t & 3) * 8;
    const float* arow = A + (size_t)(rowBlock + sr) * lda;

    f32x4 acc[2][10];
    #pragma unroll
    for (int rt = 0; rt < 2; rt++)
        #pragma unroll
        for (int ct = 0; ct < 10; ct++) acc[rt][ct] = (f32x4){0.f,0.f,0.f,0.f};

    float a8[8];
    s16x8 bvec[5];

    {
        int k = sk;
        if (k + 8 <= K) {
            float4 v0 = *(const float4*)(arow + k), v1 = *(const float4*)(arow + k + 4);
            a8[0]=v0.x; a8[1]=v0.y; a8[2]=v0.z; a8[3]=v0.w; a8[4]=v1.x; a8[5]=v1.y; a8[6]=v1.z; a8[7]=v1.w;
        } else {
            #pragma unroll
            for (int j = 0; j < 8; j++){ int kk = k + j; a8[j] = (kk < K) ? arow[kk] : 0.f; }
        }
        #pragma unroll
        for (int i = 0; i < 5; i++){
            int v = t + 256 * i;
            if (v < 1216) bvec[i] = *(const s16x8*)&Bt[(size_t)(colBlock + (v >> 2)) * bpitch + ((v & 3) * 8)];
        }
        s16x8 pv;
        #pragma unroll
        for (int j = 0; j < 8; j++) pv[j] = (short)f2bf(a8[j]);
        *(s16x8*)&As[0][sr * 40 + sk] = pv;
        #pragma unroll
        for (int i = 0; i < 5; i++){
            int v = t + 256 * i;
            if (v < 1216) *(s16x8*)&Bs[0][(v >> 2) * 36 + ((v & 3) * 8)] = bvec[i];
        }
    }
    __syncthreads();

    int cur = 0;
    for (int kt = 0; kt < ntiles; ++kt) {
        if (kt + 1 < ntiles) {
            int k = (kt + 1) * 32 + sk;
            if (k + 8 <= K) {
                float4 v0 = *(const float4*)(arow + k), v1 = *(const float4*)(arow + k + 4);
                a8[0]=v0.x; a8[1]=v0.y; a8[2]=v0.z; a8[3]=v0.w; a8[4]=v1.x; a8[5]=v1.y; a8[6]=v1.z; a8[7]=v1.w;
            } else {
                #pragma unroll
                for (int j = 0; j < 8; j++){ int kk = k + j; a8[j] = (kk < K) ? arow[kk] : 0.f; }
            }
            int k0 = (kt + 1) * 32;
            #pragma unroll
            for (int i = 0; i < 5; i++){
                int v = t + 256 * i;
                if (v < 1216) bvec[i] = *(const s16x8*)&Bt[(size_t)(colBlock + (v >> 2)) * bpitch + k0 + ((v & 3) * 8)];
            }
        }
        s16x8 af0 = *(s16x8*)&As[cur][(wr * 32 + (lane & 15)) * 40 + (lane >> 4) * 8];
        s16x8 af1 = *(s16x8*)&As[cur][(wr * 32 + 16 + (lane & 15)) * 40 + (lane >> 4) * 8];
        #pragma unroll
        for (int ct = 0; ct < 10; ct++) {
            if (wc == 1 && ct == 9) continue;
            int col = wc * 160 + ct * 16 + (lane & 15);
            s16x8 bf = *(s16x8*)&Bs[cur][col * 36 + (lane >> 4) * 8];
            acc[0][ct] = __builtin_amdgcn_mfma_f32_16x16x32_bf16(af0, bf, acc[0][ct], 0, 0, 0);
            acc[1][ct] = __builtin_amdgcn_mfma_f32_16x16x32_bf16(af1, bf, acc[1][ct], 0, 0, 0);
        }
        if (kt + 1 < ntiles) {
            s16x8 pv;
            #pragma unroll
            for (int j = 0; j < 8; j++) pv[j] = (short)f2bf(a8[j]);
            *(s16x8*)&As[cur ^ 1][sr * 40 + sk] = pv;
            #pragma unroll
            for (int i = 0; i < 5; i++){
                int v = t + 256 * i;
                if (v < 1216) *(s16x8*)&Bs[cur ^ 1][(v >> 2) * 36 + ((v & 3) * 8)] = bvec[i];
            }
        }
        __syncthreads();
        cur ^= 1;
    }

    #pragma unroll
    for (int ct = 0; ct < 10; ct++) {
        if (wc == 1 && ct == 9) continue;
        int col = colBlock + wc * 160 + ct * 16 + (lane & 15);
        if (col >= ncols) continue;
        #pragma unroll
        for (int rt = 0; rt < 2; rt++) {
            int row0 = rowBlock + wr * 32 + rt * 16 + (lane >> 4) * 4;
            #pragma unroll
            for (int i = 0; i < 4; i++)
                C[(size_t)(row0 + i) * ldc + col] = acc[rt][ct][i];
        }
    }
}

// ---------------------------------------------------------------------------
// B-table builders (bf16, zero-padded)
// ---------------------------------------------------------------------------
__global__ void build_btg_k(const float* __restrict__ B, int K, int N,
                            int ncpad, int pitch, unsigned short* __restrict__ Bt)
{
    int idx = blockIdx.x * 256 + threadIdx.x;
    if (idx >= ncpad * pitch) return;
    int col = idx / pitch, k = idx - col * pitch;
    float v = (col < N && k < K) ? B[(size_t)k * N + col] : 0.f;
    Bt[idx] = f2bf(v);
}
__global__ void build_btr_k(const float* __restrict__ Bm, int R, int K,
                            int rpad, int pitch, unsigned short* __restrict__ Bt)
{
    int idx = blockIdx.x * 256 + threadIdx.x;
    if (idx >= rpad * pitch) return;
    int col = idx / pitch, k = idx - col * pitch;
    float v = (col < R && k < K) ? Bm[(size_t)col * K + k] : 0.f;
    Bt[idx] = f2bf(v);
}
__global__ void build_vocab_bt_k(const float* __restrict__ cv, const float* __restrict__ td,
                                 unsigned short* __restrict__ Bt)
{
    int idx = blockIdx.x * 256 + threadIdx.x;
    if (idx >= 2128 * 320) return;
    int col = idx / 320, k = idx - col * 320;
    float v = 0.f;
    if (k < 300) {
        if (col < 2000) v = cv[(size_t)col * 300 + k];
        else if (col == 2000) v = td[k];
    }
    Bt[idx] = f2bf(v);
}

__global__ void cvt_attr8_k(const float* __restrict__ src, long rows, int K, int pitch,
                            unsigned short* __restrict__ dst)
{
    const int pg = pitch >> 3;
    long total = rows * pg;
    for (long i = (long)blockIdx.x * blockDim.x + threadIdx.x; i < total;
         i += (long)gridDim.x * blockDim.x) {
        long r = i / pg;
        int kg = (int)(i - r * pg) * 8;
        s16x8 v;
        #pragma unroll
        for (int j = 0; j < 8; j++){
            int k = kg + j;
            float x = (k < K) ? src[r * (long)K + k] : 0.f;
            v[j] = (short)f2bf(x);
        }
        *(s16x8*)&dst[r * (long)pitch + kg] = v;
    }
}

__global__ void wpad_k(const float* __restrict__ wn, const float* __restrict__ wr,
                       float* __restrict__ wnp, float* __restrict__ wrp)
{
    int i = threadIdx.x;
    if (i < 304) { wnp[i] = (i < 300) ? wn[i] : 0.f; wrp[i] = (i < 300) ? wr[i] : 0.f; }
}

template<int EPI>
__global__ void mm_naive_bt_k(const float* __restrict__ A, int lda, int M, int K,
                              const float* __restrict__ Bm, int N,
                              const float* __restrict__ bias,
                              float* __restrict__ Cf)
{
    int idx = blockIdx.x * 256 + threadIdx.x;
    if (idx >= M * N) return;
    int m = idx / N;
    int j = idx - m * N;
    const float* arow = A + (size_t)m * lda;
    const float* brow = Bm + (size_t)j * K;
    float s = 0.f;
    for (int k = 0; k < K; k++) s += arow[k] * brow[k];
    if (EPI == 0) Cf[idx] = s;
    else if (EPI == 2) Cf[idx] = eluf(s + bias[j]);
    else Cf[idx] = s + bias[j];
}

__global__ void transpose_k(const float* __restrict__ src, int R, int C,
                            float* __restrict__ dst)
{
    int idx = blockIdx.x * 256 + threadIdx.x;
    if (idx >= R * C) return;
    int r = idx / C, c = idx - r * C;
    dst[(size_t)c * R + r] = src[idx];
}

__global__ void pack_whhT_k(const float* __restrict__ W, unsigned short* __restrict__ WT)
{
    int idx = blockIdx.x * 256 + threadIdx.x;
    if (idx >= 300 * 1200) return;
    int k = idx / 1200, r = idx - k * 1200;
    WT[idx] = f2bf(W[(size_t)r * 300 + k]);
}

// ---------------------------------------------------------------------------
__global__ void softmax_rows_k(float* __restrict__ X, int nc)
{
    int row = blockIdx.x, t = threadIdx.x;
    __shared__ float red[256];
    size_t base = (size_t)row * nc;
    float m = -3.4e38f;
    for (int i = t; i < nc; i += 256) m = fmaxf(m, X[base + i]);
    red[t] = m; __syncthreads();
    for (int s = 128; s > 0; s >>= 1){ if (t < s) red[t] = fmaxf(red[t], red[t+s]); __syncthreads(); }
    float mx = red[0]; __syncthreads();
    float sm = 0.f;
    for (int i = t; i < nc; i += 256){ float e = expf(X[base + i] - mx); X[base + i] = e; sm += e; }
    red[t] = sm; __syncthreads();
    for (int s = 128; s > 0; s >>= 1){ if (t < s) red[t] += red[t+s]; __syncthreads(); }
    float inv = 1.f / red[0];
    for (int i = t; i < nc; i += 256) X[base + i] *= inv;
}

__global__ void tagged_add_k(const float* __restrict__ sim, const float* __restrict__ q,
                             float* __restrict__ tg)
{
    int idx = blockIdx.x * 256 + threadIdx.x;
    if (idx >= 960 * 300) return;
    int row = idx / 300;
    tg[idx] += sim[(size_t)row * 2001 + 2000] * q[idx];
}

// Fast persistent LSTM: sequential access (round-5 proven), widened ILP:
// k+=2 loop, 4 independent accumulators, unroll 8 (~16 loads in flight).
__global__ __launch_bounds__(640) void lstm_fast_k(
    const float* __restrict__ xW, const unsigned short* __restrict__ WT,
    const float* __restrict__ bih, const float* __restrict__ bhh,
    const int* __restrict__ lengths, float* __restrict__ encoded)
{
    __shared__ float hs[300];
    __shared__ float gs[1200];
    const int b = blockIdx.x, t = threadIdx.x;
    const int len = lengths[b];
    const bool ga = t < 600;
    const bool ha = t < 300;
    float bs0 = 0.f, bs1 = 0.f;
    if (ga) { bs0 = bih[2*t] + bhh[2*t]; bs1 = bih[2*t+1] + bhh[2*t+1]; }
    if (ha) hs[t] = 0.f;
    float c = 0.f, h = 0.f;
    __syncthreads();
    const float* xb = xW + (size_t)b * Ll * 1200;
    for (int st = 0; st < len; ++st) {
        if (ga) {
            float2 xv = *(const float2*)(xb + st * 1200 + 2 * t);   // issue early
            float d0 = 0.f, d1 = 0.f, d2 = 0.f, d3 = 0.f;
            const unsigned short* wp = WT + 2 * t;
            #pragma unroll 8
            for (int k = 0; k < 300; k += 2) {
                float hk0 = hs[k], hk1 = hs[k + 1];
                unsigned wv0 = *(const unsigned*)(wp + (size_t)k * 1200);
                unsigned wv1 = *(const unsigned*)(wp + (size_t)(k + 1) * 1200);
                d0 = fmaf(hk0, __uint_as_float(wv0 << 16), d0);
                d1 = fmaf(hk0, __uint_as_float(wv0 & 0xFFFF0000u), d1);
                d2 = fmaf(hk1, __uint_as_float(wv1 << 16), d2);
                d3 = fmaf(hk1, __uint_as_float(wv1 & 0xFFFF0000u), d3);
            }
            gs[2*t]   = xv.x + bs0 + d0 + d2;
            gs[2*t+1] = xv.y + bs1 + d1 + d3;
        }
        __syncthreads();
        if (ha) {
            float i_ = sigf(gs[t]);
            float f_ = sigf(gs[300 + t]);
            float g_ = tanhf(gs[600 + t]);
            float o_ = sigf(gs[900 + t]);
            c = f_ * c + i_ * g_;
            h = o_ * tanhf(c);
            hs[t] = h;
        }
        __syncthreads();
    }
    if (ha) encoded[b * 300 + t] = h;
}

// Persistent RNN decoder
__global__ __launch_bounds__(320) void rnn_all_k(
    const float* __restrict__ enc, const float* __restrict__ WihT,
    const float* __restrict__ WhhT,
    const float* __restrict__ bih, const float* __restrict__ bhh,
    float* __restrict__ hidden)
{
    __shared__ float es[304];
    __shared__ float hs[304];
    const int b = blockIdx.x, i = threadIdx.x;
    const bool act = i < 300;
    if (act) { es[i] = enc[b * 300 + i]; hs[i] = 0.f; }
    __syncthreads();
    float ex = 0.f;
    if (act) {
        #pragma unroll 8
        for (int k = 0; k < 300; k++)
            ex = fmaf(es[k], WihT[(size_t)k * 300 + i], ex);
        ex += bih[i] + bhh[i];
    }
    for (int it = 0; it < NI; it++) {
        __syncthreads();
        float d = 0.f;
        if (act) {
            #pragma unroll 8
            for (int k = 0; k < 300; k++)
                d = fmaf(hs[k], WhhT[(size_t)k * 300 + i], d);
        }
        float v = fmaxf(ex + d, 0.f);
        __syncthreads();
        if (act) { hs[i] = v; hidden[((size_t)b * NI + it) * 300 + i] = v; }
    }
}

__global__ __launch_bounds__(256) void scores_instr_k(
    const float* __restrict__ hidden, const float* __restrict__ tagged,
    const int* __restrict__ lengths, float* __restrict__ instr)
{
    __shared__ float sc[4][32];
    int wv = threadIdx.x >> 6;
    int wid = blockIdx.x * 4 + wv;
    int lane = threadIdx.x & 63;
    int b = wid / NI;
    const float* hr = hidden + (size_t)wid * Hh;
    float hv[5];
    #pragma unroll
    for (int p = 0; p < 5; p++){ int k = lane + p * 64; hv[p] = (k < Hh) ? hr[k] : 0.f; }
    int len = lengths[b];
    for (int l = 0; l < Ll; l++){
        const float* trw = tagged + ((size_t)b * Ll + l) * Hh;
        float s = 0.f;
        #pragma unroll
        for (int p = 0; p < 5; p++){ int k = lane + p * 64; if (k < Hh) s += hv[p] * trw[k]; }
        s = wave_sum(s);
        if (lane == 0) sc[wv][l] = s;
    }
    __syncthreads();
    float mx = -3.4e38f;
    for (int l = 0; l < len; l++) mx = fmaxf(mx, sc[wv][l]);
    float sum = 0.f;
    for (int l = 0; l < len; l++) sum += expf(sc[wv][l] - mx);
    float inv = 1.f / sum;
    float a[5] = {0.f,0.f,0.f,0.f,0.f};
    for (int l = 0; l < len; l++){
        float pl = expf(sc[wv][l] - mx) * inv;
        const float* trw = tagged + ((size_t)b * Ll + l) * Hh;
        #pragma unroll
        for (int p = 0; p < 5; p++){ int k = lane + p * 64; if (k < Hh) a[p] += pl * trw[k]; }
    }
    #pragma unroll
    for (int p = 0; p < 5; p++){ int k = lane + p * 64; if (k < Hh) instr[(size_t)wid * Hh + k] = a[p]; }
}

// All 5 steps' prop softmax in one launch: wid = b*NI+ii over [0,160)
__global__ __launch_bounds__(256) void prop_softmax_all_k(
    const float* __restrict__ instr, const float* __restrict__ pemb,
    float* __restrict__ psim5, float* __restrict__ rsim5)
{
    int wid = blockIdx.x * 4 + (threadIdx.x >> 6);   // b*5+ii, 0..159
    int lane = threadIdx.x & 63;
    const float* ir = instr + (size_t)wid * Hh;      // instr is [B][NI][H] flat
    float iv[5];
    #pragma unroll
    for (int p = 0; p < 5; p++){ int k = lane + p * 64; iv[p] = (k < Hh) ? ir[k] : 0.f; }
    float e[9];
    #pragma unroll
    for (int j = 0; j < 9; j++){
        const float* pr = pemb + j * Hh;
        float s = 0.f;
        #pragma unroll
        for (int p = 0; p < 5; p++){ int k = lane + p * 64; if (k < Hh) s += iv[p] * pr[k]; }
        e[j] = wave_sum(s);
    }
    if (lane == 0){
        float mx = e[0];
        #pragma unroll
        for (int j = 1; j < 9; j++) mx = fmaxf(mx, e[j]);
        float sum = 0.f;
        #pragma unroll
        for (int j = 0; j < 9; j++){ e[j] = expf(e[j] - mx); sum += e[j]; }
        float inv = 1.f / sum;
        #pragma unroll
        for (int p = 0; p < 8; p++) psim5[wid * 8 + p] = e[p] * inv;
        rsim5[wid] = e[8] * inv;
    }
}

// iscale for all 4 steps: iscale4[step][b][2400]
__global__ void iscale4_k(const float* __restrict__ instr,
                          const float* __restrict__ psim5, float* __restrict__ iscale4)
{
    int idx = blockIdx.x * 256 + threadIdx.x;   // < 4*32*2400
    if (idx >= 4 * Bb * 2400) return;
    int step = idx / (Bb * 2400);
    int r = idx - step * (Bb * 2400);
    int b = r / 2400; int k = r - b * 2400;
    int p = k / 300;  int h = k - p * 300;
    iscale4[idx] = instr[((size_t)b * NI + step) * Hh + h] * psim5[(b * NI + step) * 8 + p];
}

__global__ void count_k(const int* __restrict__ ni, int* __restrict__ cnt)
{
    int n = blockIdx.x * 256 + threadIdx.x;
    if (n < Nn) atomicAdd(&cnt[ni[n]], 1);
}
__global__ void dist_init_k(const int* __restrict__ ni, const int* __restrict__ cnt,
                            float* __restrict__ dist)
{
    int n = blockIdx.x * 256 + threadIdx.x;
    if (n < Nn) dist[n] = 1.f / (float)cnt[ni[n]];
}

__global__ void edge_msg_k(const int* __restrict__ ei, const float* __restrict__ es,
                           const float* __restrict__ dist, float* __restrict__ msgdot)
{
    int e = blockIdx.x * 256 + threadIdx.x;
    if (e < Ee){
        int s = ei[e];
        int d = ei[Ee + e];
        atomicAdd(&msgdot[d], dist[s] * es[e]);
    }
}

__global__ __launch_bounds__(256) void seg_update_k(
    const float* __restrict__ nscore, const float* __restrict__ msgdot,
    const float* __restrict__ rsim5, int step, float* __restrict__ dist)
{
    int b = blockIdx.x, t = threadIdx.x;
    __shared__ float red[256];
    int n0 = b * NPG;
    float a1 = nscore[n0 + t], a2 = nscore[n0 + 256 + t];
    float m1 = msgdot[n0 + t], m2 = msgdot[n0 + 256 + t];

    red[t] = fmaxf(a1, a2); __syncthreads();
    for (int s = 128; s > 0; s >>= 1){ if (t < s) red[t] = fmaxf(red[t], red[t+s]); __syncthreads(); }
    float mN = red[0]; __syncthreads();
    float e1 = expf(a1 - mN), e2 = expf(a2 - mN);
    red[t] = e1 + e2; __syncthreads();
    for (int s = 128; s > 0; s >>= 1){ if (t < s) red[t] += red[t+s]; __syncthreads(); }
    float sN = red[0]; __syncthreads();

    red[t] = fmaxf(m1, m2); __syncthreads();
    for (int s = 128; s > 0; s >>= 1){ if (t < s) red[t] = fmaxf(red[t], red[t+s]); __syncthreads(); }
    float mM = red[0]; __syncthreads();
    float f1 = expf(m1 - mM), f2 = expf(m2 - mM);
    red[t] = f1 + f2; __syncthreads();
    for (int s = 128; s > 0; s >>= 1){ if (t < s) red[t] += red[t+s]; __syncthreads(); }
    float sM = red[0];

    float rs = rsim5[b * NI + step];
    dist[n0 + t]       = rs * (f1 / sM) + (1.f - rs) * (e1 / sN);
    dist[n0 + 256 + t] = rs * (f2 / sM) + (1.f - rs) * (e2 / sN);
}

// final aggregation from bf16 attrs (bigws path)
__global__ __launch_bounds__(320) void final_agg_bf_k(
    const float* __restrict__ psim5, const float* __restrict__ dist,
    const unsigned short* __restrict__ nab, float* __restrict__ agg)
{
    int chunk = blockIdx.x;
    int b = blockIdx.y;
    int h = threadIdx.x;
    if (h >= Hh) return;
    float ps[8];
    #pragma unroll
    for (int p = 0; p < 8; p++) ps[p] = psim5[(b * NI + 4) * 8 + p];
    float acc = 0.f;
    for (int i = 0; i < 32; i++){
        int n = b * NPG + chunk * 32 + i;
        const unsigned short* row = nab + (size_t)n * 2400;
        float wsum = 0.f;
        #pragma unroll
        for (int p = 0; p < 8; p++) wsum += ps[p] * bf2f(row[p * Hh + h]);
        acc += dist[n] * wsum;
    }
    atomicAdd(&agg[b * Hh + h], acc);
}
// f32 fallback
__global__ __launch_bounds__(320) void final_agg_k(
    const float* __restrict__ psim5, const float* __restrict__ dist,
    const float* __restrict__ na, float* __restrict__ agg)
{
    int chunk = blockIdx.x;
    int b = blockIdx.y;
    int h = threadIdx.x;
    if (h >= Hh) return;
    float ps[8];
    #pragma unroll
    for (int p = 0; p < 8; p++) ps[p] = psim5[(b * NI + 4) * 8 + p];
    float acc = 0.f;
    for (int i = 0; i < 32; i++){
        int n = b * NPG + chunk * 32 + i;
        const float* row = na + (size_t)n * Pp * Hh;
        float wsum = 0.f;
        #pragma unroll
        for (int p = 0; p < 8; p++) wsum += ps[p] * row[p * Hh + h];
        acc += dist[n] * wsum;
    }
    atomicAdd(&agg[b * Hh + h], acc);
}

__global__ void feats_k(const float* __restrict__ enc, const float* __restrict__ agg,
                        float* __restrict__ feats)
{
    int idx = blockIdx.x * 256 + threadIdx.x;
    if (idx >= Bb * 600) return;
    int b = idx / 600, j = idx - b * 600;
    feats[idx] = (j < 300) ? enc[b * 300 + j] : agg[b * 300 + (j - 300)];
}

// ---------------------------------------------------------------------------
extern "C" void kernel_launch(void* const* d_in, const int* in_sizes, int n_in,
                              void* d_out, int out_size, void* d_ws, size_t ws_size,
                              hipStream_t stream)
{
    const float* questions      = (const float*)d_in[0];
    const int*   lengths        = (const int*)  d_in[1];
    const int*   node_indices   = (const int*)  d_in[2];
    const int*   edge_indices   = (const int*)  d_in[3];
    const int*   edge_batch     = (const int*)  d_in[4];
    const float* node_attrs     = (const float*)d_in[5];
    const float* edge_attrs     = (const float*)d_in[6];
    const float* concept_vocab  = (const float*)d_in[7];
    const float* prop_emb       = (const float*)d_in[8];
    const float* tagger_default = (const float*)d_in[9];
    const float* tagger_weight  = (const float*)d_in[10];
    const float* lstm_Wih       = (const float*)d_in[11];
    const float* lstm_Whh       = (const float*)d_in[12];
    const float* lstm_bih       = (const float*)d_in[13];
    const float* lstm_bhh       = (const float*)d_in[14];
    const float* rnn_Wih        = (const float*)d_in[15];
    const float* rnn_Whh        = (const float*)d_in[16];
    const float* rnn_bih        = (const float*)d_in[17];
    const float* rnn_bhh        = (const float*)d_in[18];
    const float* Wnp            = (const float*)d_in[19];
    const float* Wedge          = (const float*)d_in[20];
    const float* w_nscore       = (const float*)d_in[21];
    const float* w_rscore       = (const float*)d_in[22];
    const float* fc1_W          = (const float*)d_in[23];
    const float* fc1_b          = (const float*)d_in[24];
    const float* fc2_W          = (const float*)d_in[25];
    const float* fc2_b          = (const float*)d_in[26];
    float* outf = (float*)d_out;

    float* ws = (float*)d_ws;
    size_t off = 0;
    auto alloc = [&](size_t n){ size_t r = off; off += (n + 63) & ~(size_t)63; return r; };
    size_t o_q2     = alloc(960 * 300);
    size_t o_sim    = alloc((size_t)960 * 2001);
    size_t o_tagged = alloc(960 * 300);
    size_t o_xw     = alloc((size_t)960 * 1200);
    size_t o_enc    = alloc(9600);
    size_t o_hidden = alloc(48000);
    size_t o_instr  = alloc(48000);
    size_t o_psim5  = alloc(1280);                    // [B][NI][8]
    size_t o_rsim5  = alloc(160);                     // [B][NI]
    size_t o_iscl4  = alloc((size_t)4 * Bb * 2400);   // [4][B][2400]
    size_t o_nsc4   = alloc((size_t)4 * Nn);          // [4][Nn]
    size_t o_es4    = alloc((size_t)4 * Ee);          // [4][Ee]
    size_t o_msgdot = alloc(Nn);
    size_t o_dist   = alloc(Nn);
    size_t o_cnt    = alloc(64);
    size_t o_agg    = alloc(9600);
    size_t o_feats  = alloc(19200);
    size_t o_z      = alloc(19200);
    size_t o_btn    = alloc((size_t)304 * 2400 / 2);
    size_t o_bte    = alloc((size_t)304 * 320 / 2);
    size_t o_wn     = alloc(304);
    size_t o_wr     = alloc(304);
    size_t o_wlstm  = alloc(180000);
    size_t o_rwhhT  = alloc(90000);
    size_t o_rwihT  = alloc(90000);
    size_t o_btq    = alloc((size_t)304 * 320 / 2);
    size_t o_btv    = alloc((size_t)2128 * 320 / 2);
    size_t o_btc    = alloc((size_t)304 * 2016 / 2);
    size_t o_btw    = alloc((size_t)1216 * 320 / 2);
    size_t o_nab    = alloc((size_t)Nn * 2400 / 2);
    size_t o_eab    = alloc((size_t)Ee * 320 / 2);
    const bool bigws = ws_size >= off * sizeof(float);

    unsigned short* btn = (unsigned short*)(ws + o_btn);
    unsigned short* bte = (unsigned short*)(ws + o_bte);
    unsigned short* wlstm = (unsigned short*)(ws + o_wlstm);
    unsigned short* btq = (unsigned short*)(ws + o_btq);
    unsigned short* btv = (unsigned short*)(ws + o_btv);
    unsigned short* btc = (unsigned short*)(ws + o_btc);
    unsigned short* btw = (unsigned short*)(ws + o_btw);
    unsigned short* nab = (unsigned short*)(ws + o_nab);
    unsigned short* eab = (unsigned short*)(ws + o_eab);

    // ---- one-time conversions ----
    build_btg_k<<<(304*2400 + 255)/256, 256, 0, stream>>>(Wnp, 2400, 300, 304, 2400, btn);
    build_btg_k<<<(304*320 + 255)/256, 256, 0, stream>>>(Wedge, 300, 300, 304, 320, bte);
    wpad_k<<<1, 320, 0, stream>>>(w_nscore, w_rscore, ws + o_wn, ws + o_wr);
    pack_whhT_k<<<(300*1200 + 255)/256, 256, 0, stream>>>(lstm_Whh, wlstm);
    transpose_k<<<(300*300 + 255)/256, 256, 0, stream>>>(rnn_Whh, 300, 300, ws + o_rwhhT);
    transpose_k<<<(300*300 + 255)/256, 256, 0, stream>>>(rnn_Wih, 300, 300, ws + o_rwihT);
    build_btg_k<<<(304*320 + 255)/256, 256, 0, stream>>>(tagger_weight, 300, 300, 304, 320, btq);
    build_vocab_bt_k<<<(2128*320 + 255)/256, 256, 0, stream>>>(concept_vocab, tagger_default, btv);
    build_btg_k<<<(304*2016 + 255)/256, 256, 0, stream>>>(concept_vocab, 2000, 300, 304, 2016, btc);
    build_btr_k<<<(1216*320 + 255)/256, 256, 0, stream>>>(lstm_Wih, 1200, 300, 1216, 320, btw);
    if (bigws) {
        cvt_attr8_k<<<2048, 256, 0, stream>>>(node_attrs, Nn, 2400, 2400, nab);
        cvt_attr8_k<<<2048, 256, 0, stream>>>(edge_attrs, Ee, 300, 320, eab);
    }

    // ---- tagger chain (all MFMA) ----
    mfma_gemm_k<<<dim3(15,1), 256, 0, stream>>>(
        questions, 300, 300, 10, btq, 320, 300, ws + o_q2, 300);
    mfma_gemm_k<<<dim3(15,7), 256, 0, stream>>>(
        ws + o_q2, 300, 300, 10, btv, 320, 2001, ws + o_sim, 2001);
    softmax_rows_k<<<960, 256, 0, stream>>>(ws + o_sim, 2001);
    mfma_gemm_k<<<dim3(15,1), 256, 0, stream>>>(
        ws + o_sim, 2001, 2000, 63, btc, 2016, 300, ws + o_tagged, 300);
    tagged_add_k<<<1125, 256, 0, stream>>>(ws + o_sim, questions, ws + o_tagged);

    // ---- LSTM ----
    mfma_gemm_k<<<dim3(15,4), 256, 0, stream>>>(
        ws + o_tagged, 300, 300, 10, btw, 320, 1200, ws + o_xw, 1200);
    lstm_fast_k<<<Bb, 640, 0, stream>>>(ws + o_xw, wlstm, lstm_bih, lstm_bhh,
                                        lengths, ws + o_enc);

    // ---- RNN instruction decoder + instructions ----
    rnn_all_k<<<Bb, 320, 0, stream>>>(ws + o_enc, ws + o_rwihT, ws + o_rwhhT,
                                      rnn_bih, rnn_bhh, ws + o_hidden);
    scores_instr_k<<<40, 256, 0, stream>>>(ws + o_hidden, ws + o_tagged, lengths, ws + o_instr);

    // ---- distribution init ----
    hipMemsetAsync(ws + o_cnt, 0, 32 * sizeof(int), stream);
    count_k<<<64, 256, 0, stream>>>(node_indices, (int*)(ws + o_cnt));
    dist_init_k<<<64, 256, 0, stream>>>(node_indices, (int*)(ws + o_cnt), ws + o_dist);

    // ---- hoisted data-parallel phase: all prop softmaxes, scales, 8 GEMMs ----
    prop_softmax_all_k<<<40, 256, 0, stream>>>(ws + o_instr, prop_emb, ws + o_psim5, ws + o_rsim5);
    iscale4_k<<<(4*Bb*2400 + 255)/256, 256, 0, stream>>>(ws + o_instr, ws + o_psim5, ws + o_iscl4);
    for (int step = 0; step < 4; step++){
        if (bigws) {
            mfma_node_k<<<Nn/64, 256, 0, stream>>>(
                nab, btn, ws + o_iscl4 + (size_t)step * Bb * 2400, node_indices,
                ws + o_wn, ws + o_nsc4 + (size_t)step * Nn);
            mfma_edge_k<<<Ee/64, 256, 0, stream>>>(
                eab, bte, ws + o_instr + step * 300, edge_batch,
                ws + o_wr, ws + o_es4 + (size_t)step * Ee);
        } else {
            mfma_node_f_k<<<Nn/64, 256, 0, stream>>>(
                node_attrs, btn, ws + o_iscl4 + (size_t)step * Bb * 2400, node_indices,
                ws + o_wn, ws + o_nsc4 + (size_t)step * Nn);
            mfma_edge_f_k<<<Ee/64, 256, 0, stream>>>(
                edge_attrs, bte, ws + o_instr + step * 300, edge_batch,
                ws + o_wr, ws + o_es4 + (size_t)step * Ee);
        }
    }

    // ---- serial message-passing loop (tiny kernels only) ----
    for (int step = 0; step < 4; step++){
        hipMemsetAsync(ws + o_msgdot, 0, Nn * sizeof(float), stream);
        edge_msg_k<<<512, 256, 0, stream>>>(edge_indices, ws + o_es4 + (size_t)step * Ee,
                                            ws + o_dist, ws + o_msgdot);
        seg_update_k<<<32, 256, 0, stream>>>(ws + o_nsc4 + (size_t)step * Nn, ws + o_msgdot,
                                             ws + o_rsim5, step, ws + o_dist);
    }

    // ---- final aggregation + FCs ----
    hipMemsetAsync(ws + o_agg, 0, 9600 * sizeof(float), stream);
    if (bigws)
        final_agg_bf_k<<<dim3(16,32), 320, 0, stream>>>(ws + o_psim5, ws + o_dist, nab, ws + o_agg);
    else
        final_agg_k<<<dim3(16,32), 320, 0, stream>>>(ws + o_psim5, ws + o_dist, node_attrs, ws + o_agg);
    feats_k<<<75, 256, 0, stream>>>(ws + o_enc, ws + o_agg, ws + o_feats);
    mm_naive_bt_k<2><<<75, 256, 0, stream>>>(
        ws + o_feats, 600, 32, 600, fc1_W, 600, fc1_b, ws + o_z);
    mm_naive_bt_k<3><<<(32*1845 + 255)/256, 256, 0, stream>>>(
        ws + o_z, 600, 32, 600, fc2_W, 1845, fc2_b, outf);
}

// Round 9
// 1816.269 us; speedup vs baseline: 2.9494x; 1.0079x over previous
//
#include <hip/hip_runtime.h>
#include <hip/hip_bf16.h>
#include <math.h>

// Problem constants (fixed by setup_inputs)
#define Bb   32
#define Ll   30
#define Hh   300
#define Pp   8
#define Nn   16384
#define Ee   131072
#define NPG  512
#define NI   5

typedef __attribute__((ext_vector_type(4))) float f32x4;
typedef __attribute__((ext_vector_type(8))) short s16x8;

__device__ __forceinline__ float eluf(float x){ return x > 0.f ? x : expm1f(x); }
__device__ __forceinline__ float sigf(float x){ return 1.f/(1.f+expf(-x)); }
__device__ __forceinline__ float wave_sum(float s){
    s += __shfl_xor(s, 32); s += __shfl_xor(s, 16); s += __shfl_xor(s, 8);
    s += __shfl_xor(s, 4);  s += __shfl_xor(s, 2);  s += __shfl_xor(s, 1);
    return s;
}
__device__ __forceinline__ unsigned short f2bf(float x){
    unsigned u = __float_as_uint(x);
    unsigned r = u + 0x7FFFu + ((u >> 16) & 1u);
    return (unsigned short)(r >> 16);
}
__device__ __forceinline__ float bf2f(unsigned short v){
    return __uint_as_float(((unsigned)v) << 16);
}

// ---------------------------------------------------------------------------
// A-tile fetch: fills a8 (A values as f32) and s8 (scale values).
// ---------------------------------------------------------------------------
template<int KK, bool BFA>
__device__ __forceinline__ void fetch_as(const float* __restrict__ arowf,
                                         const unsigned short* __restrict__ arowb,
                                         const float* __restrict__ srow,
                                         int k, float* a8, float* s8)
{
    if constexpr (BFA) {
        s16x8 av = *(const s16x8*)(arowb + k);
        float4 w0 = *(const float4*)(srow + k), w1 = *(const float4*)(srow + k + 4);
        s8[0]=w0.x; s8[1]=w0.y; s8[2]=w0.z; s8[3]=w0.w; s8[4]=w1.x; s8[5]=w1.y; s8[6]=w1.z; s8[7]=w1.w;
        #pragma unroll
        for (int j = 0; j < 8; j++) a8[j] = bf2f((unsigned short)av[j]);
    } else {
        if (k + 8 <= KK) {
            float4 v0 = *(const float4*)(arowf + k), v1 = *(const float4*)(arowf + k + 4);
            a8[0]=v0.x; a8[1]=v0.y; a8[2]=v0.z; a8[3]=v0.w; a8[4]=v1.x; a8[5]=v1.y; a8[6]=v1.z; a8[7]=v1.w;
            float4 w0 = *(const float4*)(srow + k), w1 = *(const float4*)(srow + k + 4);
            s8[0]=w0.x; s8[1]=w0.y; s8[2]=w0.z; s8[3]=w0.w; s8[4]=w1.x; s8[5]=w1.y; s8[6]=w1.z; s8[7]=w1.w;
        } else {
            #pragma unroll
            for (int j = 0; j < 8; j++){ int kk = k + j; a8[j] = (kk < KK) ? arowf[kk] : 0.f; s8[j] = (kk < KK) ? srow[kk] : 0.f; }
        }
    }
}

// ---------------------------------------------------------------------------
// MFMA scored-GEMM, 2-phase pipelined, double-buffered LDS.
// NEW wave layout: 4 waves = 4 col-quarters (80 cols each), each wave owns all
// 64 rows (acc[4 rt][5 ct]) -> block ds_reads/K-step 88 -> 36, 4 MFMA per B-read.
// out[m] = sum_c elu( sum_k A[m,k]*S[rowb[m],k] * B[k,c] ) * w[c]
// ---------------------------------------------------------------------------
template<int KK, int BPITCH, int NTILES, bool BFA>
__device__ __forceinline__ void mfma_score_impl(
    const float* __restrict__ Af, const unsigned short* __restrict__ Ab, int lda,
    const unsigned short* __restrict__ Bt,
    const float* __restrict__ S, int sstride, const int* __restrict__ rowb,
    const float* __restrict__ wpad,
    float* __restrict__ out)
{
    __shared__ unsigned short As[2][64*40];
    __shared__ unsigned short Bs[2][304*40];
    __shared__ float red[4][64];

    const int t = threadIdx.x;
    const int wc = t >> 6, lane = t & 63;        // wave = col quarter
    const int l15 = lane & 15, g = lane >> 4;
    const int rowBlock = blockIdx.x * 64;

    const int sr = t >> 2;            // A staging row 0..63
    const int sk = (t & 3) * 8;
    const int grow = rowBlock + sr;
    const int bb = rowb[grow];
    const float* arowf = nullptr;
    const unsigned short* arowb = nullptr;
    if constexpr (BFA) arowb = Ab + (size_t)grow * lda;
    else               arowf = Af + (size_t)grow * lda;
    const float* srow = S + (size_t)bb * sstride;

    f32x4 acc[4][5];
    #pragma unroll
    for (int rt = 0; rt < 4; rt++)
        #pragma unroll
        for (int ct = 0; ct < 5; ct++) acc[rt][ct] = (f32x4){0.f,0.f,0.f,0.f};

    float a8[8], s8[8];
    s16x8 bvec[5];

    // ---- prologue ----
    {
        fetch_as<KK, BFA>(arowf, arowb, srow, sk, a8, s8);
        #pragma unroll
        for (int i = 0; i < 5; i++){
            int v = t + 256 * i;
            if (v < 1216) bvec[i] = *(const s16x8*)&Bt[(size_t)(v >> 2) * BPITCH + ((v & 3) * 8)];
        }
        s16x8 pv;
        #pragma unroll
        for (int j = 0; j < 8; j++) pv[j] = (short)f2bf(a8[j] * s8[j]);
        *(s16x8*)&As[0][sr * 40 + sk] = pv;
        #pragma unroll
        for (int i = 0; i < 5; i++){
            int v = t + 256 * i;
            if (v < 1216) *(s16x8*)&Bs[0][(v >> 2) * 40 + ((v & 3) * 8)] = bvec[i];
        }
    }
    __syncthreads();

    int cur = 0;
    for (int kt = 0; kt < NTILES; ++kt) {
        if (kt + 1 < NTILES) {
            fetch_as<KK, BFA>(arowf, arowb, srow, (kt + 1) * 32 + sk, a8, s8);
            int k0 = (kt + 1) * 32;
            #pragma unroll
            for (int i = 0; i < 5; i++){
                int v = t + 256 * i;
                if (v < 1216) bvec[i] = *(const s16x8*)&Bt[(size_t)(v >> 2) * BPITCH + k0 + ((v & 3) * 8)];
            }
        }
        s16x8 af[4];
        #pragma unroll
        for (int rt = 0; rt < 4; rt++)
            af[rt] = *(s16x8*)&As[cur][(rt * 16 + l15) * 40 + g * 8];
        #pragma unroll
        for (int ct = 0; ct < 5; ct++) {
            if (wc == 3 && ct == 4) continue;         // cols >= 304 don't exist
            int col = wc * 80 + ct * 16 + l15;
            s16x8 bf = *(s16x8*)&Bs[cur][col * 40 + g * 8];
            #pragma unroll
            for (int rt = 0; rt < 4; rt++)
                acc[rt][ct] = __builtin_amdgcn_mfma_f32_16x16x32_bf16(af[rt], bf, acc[rt][ct], 0, 0, 0);
        }
        if (kt + 1 < NTILES) {
            s16x8 pv;
            #pragma unroll
            for (int j = 0; j < 8; j++) pv[j] = (short)f2bf(a8[j] * s8[j]);
            *(s16x8*)&As[cur ^ 1][sr * 40 + sk] = pv;
            #pragma unroll
            for (int i = 0; i < 5; i++){
                int v = t + 256 * i;
                if (v < 1216) *(s16x8*)&Bs[cur ^ 1][(v >> 2) * 40 + ((v & 3) * 8)] = bvec[i];
            }
        }
        __syncthreads();
        cur ^= 1;
    }

    // ---- epilogue: per-row sum of elu(C)*w ----
    // C mapping per rt: row = rt*16 + g*4 + i, col = wc*80 + ct*16 + l15
    float p[4][4];
    #pragma unroll
    for (int rt = 0; rt < 4; rt++)
        #pragma unroll
        for (int i = 0; i < 4; i++) p[rt][i] = 0.f;
    #pragma unroll
    for (int ct = 0; ct < 5; ct++) {
        if (wc == 3 && ct == 4) continue;
        int col = wc * 80 + ct * 16 + l15;
        float wv = wpad[col];
        #pragma unroll
        for (int rt = 0; rt < 4; rt++)
            #pragma unroll
            for (int i = 0; i < 4; i++)
                p[rt][i] += eluf(acc[rt][ct][i]) * wv;
    }
    #pragma unroll
    for (int m = 1; m <= 8; m <<= 1) {
        #pragma unroll
        for (int rt = 0; rt < 4; rt++)
            #pragma unroll
            for (int i = 0; i < 4; i++)
                p[rt][i] += __shfl_xor(p[rt][i], m);
    }
    if (l15 == 0) {
        #pragma unroll
        for (int rt = 0; rt < 4; rt++)
            #pragma unroll
            for (int i = 0; i < 4; i++)
                red[wc][rt * 16 + g * 4 + i] = p[rt][i];
    }
    __syncthreads();
    if (t < 64)
        out[rowBlock + t] = red[0][t] + red[1][t] + red[2][t] + red[3][t];
}

__global__ __launch_bounds__(256, 2) void mfma_node_k(
    const unsigned short* __restrict__ Ab, const unsigned short* __restrict__ Bt,
    const float* __restrict__ S, const int* __restrict__ rowb,
    const float* __restrict__ wpad, float* __restrict__ out)
{
    mfma_score_impl<2400, 2400, 75, true>(nullptr, Ab, 2400, Bt, S, 2400, rowb, wpad, out);
}
__global__ __launch_bounds__(256, 2) void mfma_edge_k(
    const unsigned short* __restrict__ Ab, const unsigned short* __restrict__ Bt,
    const float* __restrict__ S, const int* __restrict__ rowb,
    const float* __restrict__ wpad, float* __restrict__ out)
{
    mfma_score_impl<320, 320, 10, true>(nullptr, Ab, 320, Bt, S, NI * 300, rowb, wpad, out);
}
__global__ __launch_bounds__(256, 2) void mfma_node_f_k(
    const float* __restrict__ A, const unsigned short* __restrict__ Bt,
    const float* __restrict__ S, const int* __restrict__ rowb,
    const float* __restrict__ wpad, float* __restrict__ out)
{
    mfma_score_impl<2400, 2400, 75, false>(A, nullptr, 2400, Bt, S, 2400, rowb, wpad, out);
}
__global__ __launch_bounds__(256, 2) void mfma_edge_f_k(
    const float* __restrict__ A, const unsigned short* __restrict__ Bt,
    const float* __restrict__ S, const int* __restrict__ rowb,
    const float* __restrict__ wpad, float* __restrict__ out)
{
    mfma_score_impl<300, 320, 10, false>(A, nullptr, 300, Bt, S, NI * 300, rowb, wpad, out);
}

// ---------------------------------------------------------------------------
// Generic MFMA GEMM (tagger chain): C = A(f32) @ B with bf16 Bt[col][k].
// Same new wave layout.
// ---------------------------------------------------------------------------
__global__ __launch_bounds__(256, 2) void mfma_gemm_k(
    const float* __restrict__ A, int lda, int K, int ntiles,
    const unsigned short* __restrict__ Bt, int bpitch,
    int ncols, float* __restrict__ C, int ldc)
{
    __shared__ unsigned short As[2][64*40];
    __shared__ unsigned short Bs[2][304*40];

    const int t = threadIdx.x;
    const int wc = t >> 6, lane = t & 63;
    const int l15 = lane & 15, g = lane >> 4;
    const int rowBlock = blockIdx.x * 64;
    const int colBlock = blockIdx.y * 304;

    const int sr = t >> 2, sk = (t & 3) * 8;
    const float* arow = A + (size_t)(rowBlock + sr) * lda;

    f32x4 acc[4][5];
    #pragma unroll
    for (int rt = 0; rt < 4; rt++)
        #pragma unroll
        for (int ct = 0; ct < 5; ct++) acc[rt][ct] = (f32x4){0.f,0.f,0.f,0.f};

    float a8[8];
    s16x8 bvec[5];

    {
        int k = sk;
        if (k + 8 <= K) {
            float4 v0 = *(const float4*)(arow + k), v1 = *(const float4*)(arow + k + 4);
            a8[0]=v0.x; a8[1]=v0.y; a8[2]=v0.z; a8[3]=v0.w; a8[4]=v1.x; a8[5]=v1.y; a8[6]=v1.z; a8[7]=v1.w;
        } else {
            #pragma unroll
            for (int j = 0; j < 8; j++){ int kk = k + j; a8[j] = (kk < K) ? arow[kk] : 0.f; }
        }
        #pragma unroll
        for (int i = 0; i < 5; i++){
            int v = t + 256 * i;
            if (v < 1216) bvec[i] = *(const s16x8*)&Bt[(size_t)(colBlock + (v >> 2)) * bpitch + ((v & 3) * 8)];
        }
        s16x8 pv;
        #pragma unroll
        for (int j = 0; j < 8; j++) pv[j] = (short)f2bf(a8[j]);
        *(s16x8*)&As[0][sr * 40 + sk] = pv;
        #pragma unroll
        for (int i = 0; i < 5; i++){
            int v = t + 256 * i;
            if (v < 1216) *(s16x8*)&Bs[0][(v >> 2) * 40 + ((v & 3) * 8)] = bvec[i];
        }
    }
    __syncthreads();

    int cur = 0;
    for (int kt = 0; kt < ntiles; ++kt) {
        if (kt + 1 < ntiles) {
            int k = (kt + 1) * 32 + sk;
            if (k + 8 <= K) {
                float4 v0 = *(const float4*)(arow + k), v1 = *(const float4*)(arow + k + 4);
                a8[0]=v0.x; a8[1]=v0.y; a8[2]=v0.z; a8[3]=v0.w; a8[4]=v1.x; a8[5]=v1.y; a8[6]=v1.z; a8[7]=v1.w;
            } else {
                #pragma unroll
                for (int j = 0; j < 8; j++){ int kk = k + j; a8[j] = (kk < K) ? arow[kk] : 0.f; }
            }
            int k0 = (kt + 1) * 32;
            #pragma unroll
            for (int i = 0; i < 5; i++){
                int v = t + 256 * i;
                if (v < 1216) bvec[i] = *(const s16x8*)&Bt[(size_t)(colBlock + (v >> 2)) * bpitch + k0 + ((v & 3) * 8)];
            }
        }
        s16x8 af[4];
        #pragma unroll
        for (int rt = 0; rt < 4; rt++)
            af[rt] = *(s16x8*)&As[cur][(rt * 16 + l15) * 40 + g * 8];
        #pragma unroll
        for (int ct = 0; ct < 5; ct++) {
            if (wc == 3 && ct == 4) continue;
            int col = wc * 80 + ct * 16 + l15;
            s16x8 bf = *(s16x8*)&Bs[cur][col * 40 + g * 8];
            #pragma unroll
            for (int rt = 0; rt < 4; rt++)
                acc[rt][ct] = __builtin_amdgcn_mfma_f32_16x16x32_bf16(af[rt], bf, acc[rt][ct], 0, 0, 0);
        }
        if (kt + 1 < ntiles) {
            s16x8 pv;
            #pragma unroll
            for (int j = 0; j < 8; j++) pv[j] = (short)f2bf(a8[j]);
            *(s16x8*)&As[cur ^ 1][sr * 40 + sk] = pv;
            #pragma unroll
            for (int i = 0; i < 5; i++){
                int v = t + 256 * i;
                if (v < 1216) *(s16x8*)&Bs[cur ^ 1][(v >> 2) * 40 + ((v & 3) * 8)] = bvec[i];
            }
        }
        __syncthreads();
        cur ^= 1;
    }

    #pragma unroll
    for (int ct = 0; ct < 5; ct++) {
        if (wc == 3 && ct == 4) continue;
        int col = colBlock + wc * 80 + ct * 16 + l15;
        if (col >= ncols) continue;
        #pragma unroll
        for (int rt = 0; rt < 4; rt++) {
            int row0 = rowBlock + rt * 16 + g * 4;
            #pragma unroll
            for (int i = 0; i < 4; i++)
                C[(size_t)(row0 + i) * ldc + col] = acc[rt][ct][i];
        }
    }
}

// ---------------------------------------------------------------------------
// B-table builders (bf16, zero-padded)
// ---------------------------------------------------------------------------
__global__ void build_btg_k(const float* __restrict__ B, int K, int N,
                            int ncpad, int pitch, unsigned short* __restrict__ Bt)
{
    int idx = blockIdx.x * 256 + threadIdx.x;
    if (idx >= ncpad * pitch) return;
    int col = idx / pitch, k = idx - col * pitch;
    float v = (col < N && k < K) ? B[(size_t)k * N + col] : 0.f;
    Bt[idx] = f2bf(v);
}
__global__ void build_btr_k(const float* __restrict__ Bm, int R, int K,
                            int rpad, int pitch, unsigned short* __restrict__ Bt)
{
    int idx = blockIdx.x * 256 + threadIdx.x;
    if (idx >= rpad * pitch) return;
    int col = idx / pitch, k = idx - col * pitch;
    float v = (col < R && k < K) ? Bm[(size_t)col * K + k] : 0.f;
    Bt[idx] = f2bf(v);
}
__global__ void build_vocab_bt_k(const float* __restrict__ cv, const float* __restrict__ td,
                                 unsigned short* __restrict__ Bt)
{
    int idx = blockIdx.x * 256 + threadIdx.x;
    if (idx >= 2128 * 320) return;
    int col = idx / 320, k = idx - col * 320;
    float v = 0.f;
    if (k < 300) {
        if (col < 2000) v = cv[(size_t)col * 300 + k];
        else if (col == 2000) v = td[k];
    }
    Bt[idx] = f2bf(v);
}

__global__ void cvt_attr8_k(const float* __restrict__ src, long rows, int K, int pitch,
                            unsigned short* __restrict__ dst)
{
    const int pg = pitch >> 3;
    long total = rows * pg;
    for (long i = (long)blockIdx.x * blockDim.x + threadIdx.x; i < total;
         i += (long)gridDim.x * blockDim.x) {
        long r = i / pg;
        int kg = (int)(i - r * pg) * 8;
        s16x8 v;
        #pragma unroll
        for (int j = 0; j < 8; j++){
            int k = kg + j;
            float x = (k < K) ? src[r * (long)K + k] : 0.f;
            v[j] = (short)f2bf(x);
        }
        *(s16x8*)&dst[r * (long)pitch + kg] = v;
    }
}

__global__ void wpad_k(const float* __restrict__ wn, const float* __restrict__ wr,
                       float* __restrict__ wnp, float* __restrict__ wrp)
{
    int i = threadIdx.x;
    if (i < 304) { wnp[i] = (i < 300) ? wn[i] : 0.f; wrp[i] = (i < 300) ? wr[i] : 0.f; }
}

template<int EPI>
__global__ void mm_naive_bt_k(const float* __restrict__ A, int lda, int M, int K,
                              const float* __restrict__ Bm, int N,
                              const float* __restrict__ bias,
                              float* __restrict__ Cf)
{
    int idx = blockIdx.x * 256 + threadIdx.x;
    if (idx >= M * N) return;
    int m = idx / N;
    int j = idx - m * N;
    const float* arow = A + (size_t)m * lda;
    const float* brow = Bm + (size_t)j * K;
    float s = 0.f;
    for (int k = 0; k < K; k++) s += arow[k] * brow[k];
    if (EPI == 0) Cf[idx] = s;
    else if (EPI == 2) Cf[idx] = eluf(s + bias[j]);
    else Cf[idx] = s + bias[j];
}

__global__ void transpose_k(const float* __restrict__ src, int R, int C,
                            float* __restrict__ dst)
{
    int idx = blockIdx.x * 256 + threadIdx.x;
    if (idx >= R * C) return;
    int r = idx / C, c = idx - r * C;
    dst[(size_t)c * R + r] = src[idx];
}

__global__ void pack_whhT_k(const float* __restrict__ W, unsigned short* __restrict__ WT)
{
    int idx = blockIdx.x * 256 + threadIdx.x;
    if (idx >= 300 * 1200) return;
    int k = idx / 1200, r = idx - k * 1200;
    WT[idx] = f2bf(W[(size_t)r * 300 + k]);
}

// ---------------------------------------------------------------------------
__global__ void softmax_rows_k(float* __restrict__ X, int nc)
{
    int row = blockIdx.x, t = threadIdx.x;
    __shared__ float red[256];
    size_t base = (size_t)row * nc;
    float m = -3.4e38f;
    for (int i = t; i < nc; i += 256) m = fmaxf(m, X[base + i]);
    red[t] = m; __syncthreads();
    for (int s = 128; s > 0; s >>= 1){ if (t < s) red[t] = fmaxf(red[t], red[t+s]); __syncthreads(); }
    float mx = red[0]; __syncthreads();
    float sm = 0.f;
    for (int i = t; i < nc; i += 256){ float e = expf(X[base + i] - mx); X[base + i] = e; sm += e; }
    red[t] = sm; __syncthreads();
    for (int s = 128; s > 0; s >>= 1){ if (t < s) red[t] += red[t+s]; __syncthreads(); }
    float inv = 1.f / red[0];
    for (int i = t; i < nc; i += 256) X[base + i] *= inv;
}

__global__ void tagged_add_k(const float* __restrict__ sim, const float* __restrict__ q,
                             float* __restrict__ tg)
{
    int idx = blockIdx.x * 256 + threadIdx.x;
    if (idx >= 960 * 300) return;
    int row = idx / 300;
    tg[idx] += sim[(size_t)row * 2001 + 2000] * q[idx];
}

// Fast persistent LSTM (round-8 measured-good): seq access, 4 accumulators.
__global__ __launch_bounds__(640) void lstm_fast_k(
    const float* __restrict__ xW, const unsigned short* __restrict__ WT,
    const float* __restrict__ bih, const float* __restrict__ bhh,
    const int* __restrict__ lengths, float* __restrict__ encoded)
{
    __shared__ float hs[300];
    __shared__ float gs[1200];
    const int b = blockIdx.x, t = threadIdx.x;
    const int len = lengths[b];
    const bool ga = t < 600;
    const bool ha = t < 300;
    float bs0 = 0.f, bs1 = 0.f;
    if (ga) { bs0 = bih[2*t] + bhh[2*t]; bs1 = bih[2*t+1] + bhh[2*t+1]; }
    if (ha) hs[t] = 0.f;
    float c = 0.f, h = 0.f;
    __syncthreads();
    const float* xb = xW + (size_t)b * Ll * 1200;
    for (int st = 0; st < len; ++st) {
        if (ga) {
            float2 xv = *(const float2*)(xb + st * 1200 + 2 * t);
            float d0 = 0.f, d1 = 0.f, d2 = 0.f, d3 = 0.f;
            const unsigned short* wp = WT + 2 * t;
            #pragma unroll 8
            for (int k = 0; k < 300; k += 2) {
                float hk0 = hs[k], hk1 = hs[k + 1];
                unsigned wv0 = *(const unsigned*)(wp + (size_t)k * 1200);
                unsigned wv1 = *(const unsigned*)(wp + (size_t)(k + 1) * 1200);
                d0 = fmaf(hk0, __uint_as_float(wv0 << 16), d0);
                d1 = fmaf(hk0, __uint_as_float(wv0 & 0xFFFF0000u), d1);
                d2 = fmaf(hk1, __uint_as_float(wv1 << 16), d2);
                d3 = fmaf(hk1, __uint_as_float(wv1 & 0xFFFF0000u), d3);
            }
            gs[2*t]   = xv.x + bs0 + d0 + d2;
            gs[2*t+1] = xv.y + bs1 + d1 + d3;
        }
        __syncthreads();
        if (ha) {
            float i_ = sigf(gs[t]);
            float f_ = sigf(gs[300 + t]);
            float g_ = tanhf(gs[600 + t]);
            float o_ = sigf(gs[900 + t]);
            c = f_ * c + i_ * g_;
            h = o_ * tanhf(c);
            hs[t] = h;
        }
        __syncthreads();
    }
    if (ha) encoded[b * 300 + t] = h;
}

// Persistent RNN decoder
__global__ __launch_bounds__(320) void rnn_all_k(
    const float* __restrict__ enc, const float* __restrict__ WihT,
    const float* __restrict__ WhhT,
    const float* __restrict__ bih, const float* __restrict__ bhh,
    float* __restrict__ hidden)
{
    __shared__ float es[304];
    __shared__ float hs[304];
    const int b = blockIdx.x, i = threadIdx.x;
    const bool act = i < 300;
    if (act) { es[i] = enc[b * 300 + i]; hs[i] = 0.f; }
    __syncthreads();
    float ex = 0.f;
    if (act) {
        #pragma unroll 8
        for (int k = 0; k < 300; k++)
            ex = fmaf(es[k], WihT[(size_t)k * 300 + i], ex);
        ex += bih[i] + bhh[i];
    }
    for (int it = 0; it < NI; it++) {
        __syncthreads();
        float d = 0.f;
        if (act) {
            #pragma unroll 8
            for (int k = 0; k < 300; k++)
                d = fmaf(hs[k], WhhT[(size_t)k * 300 + i], d);
        }
        float v = fmaxf(ex + d, 0.f);
        __syncthreads();
        if (act) { hs[i] = v; hidden[((size_t)b * NI + it) * 300 + i] = v; }
    }
}

__global__ __launch_bounds__(256) void scores_instr_k(
    const float* __restrict__ hidden, const float* __restrict__ tagged,
    const int* __restrict__ lengths, float* __restrict__ instr)
{
    __shared__ float sc[4][32];
    int wv = threadIdx.x >> 6;
    int wid = blockIdx.x * 4 + wv;
    int lane = threadIdx.x & 63;
    int b = wid / NI;
    const float* hr = hidden + (size_t)wid * Hh;
    float hv[5];
    #pragma unroll
    for (int p = 0; p < 5; p++){ int k = lane + p * 64; hv[p] = (k < Hh) ? hr[k] : 0.f; }
    int len = lengths[b];
    for (int l = 0; l < Ll; l++){
        const float* trw = tagged + ((size_t)b * Ll + l) * Hh;
        float s = 0.f;
        #pragma unroll
        for (int p = 0; p < 5; p++){ int k = lane + p * 64; if (k < Hh) s += hv[p] * trw[k]; }
        s = wave_sum(s);
        if (lane == 0) sc[wv][l] = s;
    }
    __syncthreads();
    float mx = -3.4e38f;
    for (int l = 0; l < len; l++) mx = fmaxf(mx, sc[wv][l]);
    float sum = 0.f;
    for (int l = 0; l < len; l++) sum += expf(sc[wv][l] - mx);
    float inv = 1.f / sum;
    float a[5] = {0.f,0.f,0.f,0.f,0.f};
    for (int l = 0; l < len; l++){
        float pl = expf(sc[wv][l] - mx) * inv;
        const float* trw = tagged + ((size_t)b * Ll + l) * Hh;
        #pragma unroll
        for (int p = 0; p < 5; p++){ int k = lane + p * 64; if (k < Hh) a[p] += pl * trw[k]; }
    }
    #pragma unroll
    for (int p = 0; p < 5; p++){ int k = lane + p * 64; if (k < Hh) instr[(size_t)wid * Hh + k] = a[p]; }
}

// All 5 steps' prop softmax in one launch
__global__ __launch_bounds__(256) void prop_softmax_all_k(
    const float* __restrict__ instr, const float* __restrict__ pemb,
    float* __restrict__ psim5, float* __restrict__ rsim5)
{
    int wid = blockIdx.x * 4 + (threadIdx.x >> 6);
    int lane = threadIdx.x & 63;
    const float* ir = instr + (size_t)wid * Hh;
    float iv[5];
    #pragma unroll
    for (int p = 0; p < 5; p++){ int k = lane + p * 64; iv[p] = (k < Hh) ? ir[k] : 0.f; }
    float e[9];
    #pragma unroll
    for (int j = 0; j < 9; j++){
        const float* pr = pemb + j * Hh;
        float s = 0.f;
        #pragma unroll
        for (int p = 0; p < 5; p++){ int k = lane + p * 64; if (k < Hh) s += iv[p] * pr[k]; }
        e[j] = wave_sum(s);
    }
    if (lane == 0){
        float mx = e[0];
        #pragma unroll
        for (int j = 1; j < 9; j++) mx = fmaxf(mx, e[j]);
        float sum = 0.f;
        #pragma unroll
        for (int j = 0; j < 9; j++){ e[j] = expf(e[j] - mx); sum += e[j]; }
        float inv = 1.f / sum;
        #pragma unroll
        for (int p = 0; p < 8; p++) psim5[wid * 8 + p] = e[p] * inv;
        rsim5[wid] = e[8] * inv;
    }
}

__global__ void iscale4_k(const float* __restrict__ instr,
                          const float* __restrict__ psim5, float* __restrict__ iscale4)
{
    int idx = blockIdx.x * 256 + threadIdx.x;
    if (idx >= 4 * Bb * 2400) return;
    int step = idx / (Bb * 2400);
    int r = idx - step * (Bb * 2400);
    int b = r / 2400; int k = r - b * 2400;
    int p = k / 300;  int h = k - p * 300;
    iscale4[idx] = instr[((size_t)b * NI + step) * Hh + h] * psim5[(b * NI + step) * 8 + p];
}

__global__ void count_k(const int* __restrict__ ni, int* __restrict__ cnt)
{
    int n = blockIdx.x * 256 + threadIdx.x;
    if (n < Nn) atomicAdd(&cnt[ni[n]], 1);
}
__global__ void dist_init_k(const int* __restrict__ ni, const int* __restrict__ cnt,
                            float* __restrict__ dist)
{
    int n = blockIdx.x * 256 + threadIdx.x;
    if (n < Nn) dist[n] = 1.f / (float)cnt[ni[n]];
}

__global__ void edge_msg_k(const int* __restrict__ ei, const float* __restrict__ es,
                           const float* __restrict__ dist, float* __restrict__ msgdot)
{
    int e = blockIdx.x * 256 + threadIdx.x;
    if (e < Ee){
        int s = ei[e];
        int d = ei[Ee + e];
        atomicAdd(&msgdot[d], dist[s] * es[e]);
    }
}

// seg_update also re-zeros its msgdot range for the next iteration.
__global__ __launch_bounds__(256) void seg_update_k(
    const float* __restrict__ nscore, float* __restrict__ msgdot,
    const float* __restrict__ rsim5, int step, float* __restrict__ dist)
{
    int b = blockIdx.x, t = threadIdx.x;
    __shared__ float red[256];
    int n0 = b * NPG;
    float a1 = nscore[n0 + t], a2 = nscore[n0 + 256 + t];
    float m1 = msgdot[n0 + t], m2 = msgdot[n0 + 256 + t];

    red[t] = fmaxf(a1, a2); __syncthreads();
    for (int s = 128; s > 0; s >>= 1){ if (t < s) red[t] = fmaxf(red[t], red[t+s]); __syncthreads(); }
    float mN = red[0]; __syncthreads();
    float e1 = expf(a1 - mN), e2 = expf(a2 - mN);
    red[t] = e1 + e2; __syncthreads();
    for (int s = 128; s > 0; s >>= 1){ if (t < s) red[t] += red[t+s]; __syncthreads(); }
    float sN = red[0]; __syncthreads();

    red[t] = fmaxf(m1, m2); __syncthreads();
    for (int s = 128; s > 0; s >>= 1){ if (t < s) red[t] = fmaxf(red[t], red[t+s]); __syncthreads(); }
    float mM = red[0]; __syncthreads();
    float f1 = expf(m1 - mM), f2 = expf(m2 - mM);
    red[t] = f1 + f2; __syncthreads();
    for (int s = 128; s > 0; s >>= 1){ if (t < s) red[t] += red[t+s]; __syncthreads(); }
    float sM = red[0];

    float rs = rsim5[b * NI + step];
    dist[n0 + t]       = rs * (f1 / sM) + (1.f - rs) * (e1 / sN);
    dist[n0 + 256 + t] = rs * (f2 / sM) + (1.f - rs) * (e2 / sN);
    msgdot[n0 + t] = 0.f;
    msgdot[n0 + 256 + t] = 0.f;
}

// final aggregation from bf16 attrs (bigws path)
__global__ __launch_bounds__(320) void final_agg_bf_k(
    const float* __restrict__ psim5, const float* __restrict__ dist,
    const unsigned short* __restrict__ nab, float* __restrict__ agg)
{
    int chunk = blockIdx.x;
    int b = blockIdx.y;
    int h = threadIdx.x;
    if (h >= Hh) return;
    float ps[8];
    #pragma unroll
    for (int p = 0; p < 8; p++) ps[p] = psim5[(b * NI + 4) * 8 + p];
    float acc = 0.f;
    for (int i = 0; i < 32; i++){
        int n = b * NPG + chunk * 32 + i;
        const unsigned short* row = nab + (size_t)n * 2400;
        float wsum = 0.f;
        #pragma unroll
        for (int p = 0; p < 8; p++) wsum += ps[p] * bf2f(row[p * Hh + h]);
        acc += dist[n] * wsum;
    }
    atomicAdd(&agg[b * Hh + h], acc);
}
__global__ __launch_bounds__(320) void final_agg_k(
    const float* __restrict__ psim5, const float* __restrict__ dist,
    const float* __restrict__ na, float* __restrict__ agg)
{
    int chunk = blockIdx.x;
    int b = blockIdx.y;
    int h = threadIdx.x;
    if (h >= Hh) return;
    float ps[8];
    #pragma unroll
    for (int p = 0; p < 8; p++) ps[p] = psim5[(b * NI + 4) * 8 + p];
    float acc = 0.f;
    for (int i = 0; i < 32; i++){
        int n = b * NPG + chunk * 32 + i;
        const float* row = na + (size_t)n * Pp * Hh;
        float wsum = 0.f;
        #pragma unroll
        for (int p = 0; p < 8; p++) wsum += ps[p] * row[p * Hh + h];
        acc += dist[n] * wsum;
    }
    atomicAdd(&agg[b * Hh + h], acc);
}

__global__ void feats_k(const float* __restrict__ enc, const float* __restrict__ agg,
                        float* __restrict__ feats)
{
    int idx = blockIdx.x * 256 + threadIdx.x;
    if (idx >= Bb * 600) return;
    int b = idx / 600, j = idx - b * 600;
    feats[idx] = (j < 300) ? enc[b * 300 + j] : agg[b * 300 + (j - 300)];
}

// ---------------------------------------------------------------------------
extern "C" void kernel_launch(void* const* d_in, const int* in_sizes, int n_in,
                              void* d_out, int out_size, void* d_ws, size_t ws_size,
                              hipStream_t stream)
{
    const float* questions      = (const float*)d_in[0];
    const int*   lengths        = (const int*)  d_in[1];
    const int*   node_indices   = (const int*)  d_in[2];
    const int*   edge_indices   = (const int*)  d_in[3];
    const int*   edge_batch     = (const int*)  d_in[4];
    const float* node_attrs     = (const float*)d_in[5];
    const float* edge_attrs     = (const float*)d_in[6];
    const float* concept_vocab  = (const float*)d_in[7];
    const float* prop_emb       = (const float*)d_in[8];
    const float* tagger_default = (const float*)d_in[9];
    const float* tagger_weight  = (const float*)d_in[10];
    const float* lstm_Wih       = (const float*)d_in[11];
    const float* lstm_Whh       = (const float*)d_in[12];
    const float* lstm_bih       = (const float*)d_in[13];
    const float* lstm_bhh       = (const float*)d_in[14];
    const float* rnn_Wih        = (const float*)d_in[15];
    const float* rnn_Whh        = (const float*)d_in[16];
    const float* rnn_bih        = (const float*)d_in[17];
    const float* rnn_bhh        = (const float*)d_in[18];
    const float* Wnp            = (const float*)d_in[19];
    const float* Wedge          = (const float*)d_in[20];
    const float* w_nscore       = (const float*)d_in[21];
    const float* w_rscore       = (const float*)d_in[22];
    const float* fc1_W          = (const float*)d_in[23];
    const float* fc1_b          = (const float*)d_in[24];
    const float* fc2_W          = (const float*)d_in[25];
    const float* fc2_b          = (const float*)d_in[26];
    float* outf = (float*)d_out;

    float* ws = (float*)d_ws;
    size_t off = 0;
    auto alloc = [&](size_t n){ size_t r = off; off += (n + 63) & ~(size_t)63; return r; };
    size_t o_q2     = alloc(960 * 300);
    size_t o_sim    = alloc((size_t)960 * 2001);
    size_t o_tagged = alloc(960 * 300);
    size_t o_xw     = alloc((size_t)960 * 1200);
    size_t o_enc    = alloc(9600);
    size_t o_hidden = alloc(48000);
    size_t o_instr  = alloc(48000);
    size_t o_psim5  = alloc(1280);
    size_t o_rsim5  = alloc(160);
    size_t o_iscl4  = alloc((size_t)4 * Bb * 2400);
    size_t o_nsc4   = alloc((size_t)4 * Nn);
    size_t o_es4    = alloc((size_t)4 * Ee);
    size_t o_msgdot = alloc(Nn);
    size_t o_dist   = alloc(Nn);
    size_t o_cnt    = alloc(64);
    size_t o_agg    = alloc(9600);
    size_t o_feats  = alloc(19200);
    size_t o_z      = alloc(19200);
    size_t o_btn    = alloc((size_t)304 * 2400 / 2);
    size_t o_bte    = alloc((size_t)304 * 320 / 2);
    size_t o_wn     = alloc(304);
    size_t o_wr     = alloc(304);
    size_t o_wlstm  = alloc(180000);
    size_t o_rwhhT  = alloc(90000);
    size_t o_rwihT  = alloc(90000);
    size_t o_btq    = alloc((size_t)304 * 320 / 2);
    size_t o_btv    = alloc((size_t)2128 * 320 / 2);
    size_t o_btc    = alloc((size_t)304 * 2016 / 2);
    size_t o_btw    = alloc((size_t)1216 * 320 / 2);
    size_t o_nab    = alloc((size_t)Nn * 2400 / 2);
    size_t o_eab    = alloc((size_t)Ee * 320 / 2);
    const bool bigws = ws_size >= off * sizeof(float);

    unsigned short* btn = (unsigned short*)(ws + o_btn);
    unsigned short* bte = (unsigned short*)(ws + o_bte);
    unsigned short* wlstm = (unsigned short*)(ws + o_wlstm);
    unsigned short* btq = (unsigned short*)(ws + o_btq);
    unsigned short* btv = (unsigned short*)(ws + o_btv);
    unsigned short* btc = (unsigned short*)(ws + o_btc);
    unsigned short* btw = (unsigned short*)(ws + o_btw);
    unsigned short* nab = (unsigned short*)(ws + o_nab);
    unsigned short* eab = (unsigned short*)(ws + o_eab);

    // ---- one-time conversions ----
    build_btg_k<<<(304*2400 + 255)/256, 256, 0, stream>>>(Wnp, 2400, 300, 304, 2400, btn);
    build_btg_k<<<(304*320 + 255)/256, 256, 0, stream>>>(Wedge, 300, 300, 304, 320, bte);
    wpad_k<<<1, 320, 0, stream>>>(w_nscore, w_rscore, ws + o_wn, ws + o_wr);
    pack_whhT_k<<<(300*1200 + 255)/256, 256, 0, stream>>>(lstm_Whh, wlstm);
    transpose_k<<<(300*300 + 255)/256, 256, 0, stream>>>(rnn_Whh, 300, 300, ws + o_rwhhT);
    transpose_k<<<(300*300 + 255)/256, 256, 0, stream>>>(rnn_Wih, 300, 300, ws + o_rwihT);
    build_btg_k<<<(304*320 + 255)/256, 256, 0, stream>>>(tagger_weight, 300, 300, 304, 320, btq);
    build_vocab_bt_k<<<(2128*320 + 255)/256, 256, 0, stream>>>(concept_vocab, tagger_default, btv);
    build_btg_k<<<(304*2016 + 255)/256, 256, 0, stream>>>(concept_vocab, 2000, 300, 304, 2016, btc);
    build_btr_k<<<(1216*320 + 255)/256, 256, 0, stream>>>(lstm_Wih, 1200, 300, 1216, 320, btw);
    if (bigws) {
        cvt_attr8_k<<<2048, 256, 0, stream>>>(node_attrs, Nn, 2400, 2400, nab);
        cvt_attr8_k<<<2048, 256, 0, stream>>>(edge_attrs, Ee, 300, 320, eab);
    }

    // ---- tagger chain (all MFMA) ----
    mfma_gemm_k<<<dim3(15,1), 256, 0, stream>>>(
        questions, 300, 300, 10, btq, 320, 300, ws + o_q2, 300);
    mfma_gemm_k<<<dim3(15,7), 256, 0, stream>>>(
        ws + o_q2, 300, 300, 10, btv, 320, 2001, ws + o_sim, 2001);
    softmax_rows_k<<<960, 256, 0, stream>>>(ws + o_sim, 2001);
    mfma_gemm_k<<<dim3(15,1), 256, 0, stream>>>(
        ws + o_sim, 2001, 2000, 63, btc, 2016, 300, ws + o_tagged, 300);
    tagged_add_k<<<1125, 256, 0, stream>>>(ws + o_sim, questions, ws + o_tagged);

    // ---- LSTM ----
    mfma_gemm_k<<<dim3(15,4), 256, 0, stream>>>(
        ws + o_tagged, 300, 300, 10, btw, 320, 1200, ws + o_xw, 1200);
    lstm_fast_k<<<Bb, 640, 0, stream>>>(ws + o_xw, wlstm, lstm_bih, lstm_bhh,
                                        lengths, ws + o_enc);

    // ---- RNN instruction decoder + instructions ----
    rnn_all_k<<<Bb, 320, 0, stream>>>(ws + o_enc, ws + o_rwihT, ws + o_rwhhT,
                                      rnn_bih, rnn_bhh, ws + o_hidden);
    scores_instr_k<<<40, 256, 0, stream>>>(ws + o_hidden, ws + o_tagged, lengths, ws + o_instr);

    // ---- distribution init ----
    hipMemsetAsync(ws + o_cnt, 0, 32 * sizeof(int), stream);
    count_k<<<64, 256, 0, stream>>>(node_indices, (int*)(ws + o_cnt));
    dist_init_k<<<64, 256, 0, stream>>>(node_indices, (int*)(ws + o_cnt), ws + o_dist);

    // ---- hoisted data-parallel phase: all prop softmaxes, scales, 8 GEMMs ----
    prop_softmax_all_k<<<40, 256, 0, stream>>>(ws + o_instr, prop_emb, ws + o_psim5, ws + o_rsim5);
    iscale4_k<<<(4*Bb*2400 + 255)/256, 256, 0, stream>>>(ws + o_instr, ws + o_psim5, ws + o_iscl4);
    for (int step = 0; step < 4; step++){
        if (bigws) {
            mfma_node_k<<<Nn/64, 256, 0, stream>>>(
                nab, btn, ws + o_iscl4 + (size_t)step * Bb * 2400, node_indices,
                ws + o_wn, ws + o_nsc4 + (size_t)step * Nn);
            mfma_edge_k<<<Ee/64, 256, 0, stream>>>(
                eab, bte, ws + o_instr + step * 300, edge_batch,
                ws + o_wr, ws + o_es4 + (size_t)step * Ee);
        } else {
            mfma_node_f_k<<<Nn/64, 256, 0, stream>>>(
                node_attrs, btn, ws + o_iscl4 + (size_t)step * Bb * 2400, node_indices,
                ws + o_wn, ws + o_nsc4 + (size_t)step * Nn);
            mfma_edge_f_k<<<Ee/64, 256, 0, stream>>>(
                edge_attrs, bte, ws + o_instr + step * 300, edge_batch,
                ws + o_wr, ws + o_es4 + (size_t)step * Ee);
        }
    }

    // ---- serial message-passing loop (tiny kernels only) ----
    hipMemsetAsync(ws + o_msgdot, 0, Nn * sizeof(float), stream);
    for (int step = 0; step < 4; step++){
        edge_msg_k<<<512, 256, 0, stream>>>(edge_indices, ws + o_es4 + (size_t)step * Ee,
                                            ws + o_dist, ws + o_msgdot);
        seg_update_k<<<32, 256, 0, stream>>>(ws + o_nsc4 + (size_t)step * Nn, ws + o_msgdot,
                                             ws + o_rsim5, step, ws + o_dist);
    }

    // ---- final aggregation + FCs ----
    hipMemsetAsync(ws + o_agg, 0, 9600 * sizeof(float), stream);
    if (bigws)
        final_agg_bf_k<<<dim3(16,32), 320, 0, stream>>>(ws + o_psim5, ws + o_dist, nab, ws + o_agg);
    else
        final_agg_k<<<dim3(16,32), 320, 0, stream>>>(ws + o_psim5, ws + o_dist, node_attrs, ws + o_agg);
    feats_k<<<75, 256, 0, stream>>>(ws + o_enc, ws + o_agg, ws + o_feats);
    mm_naive_bt_k<2><<<75, 256, 0, stream>>>(
        ws + o_feats, 600, 32, 600, fc1_W, 600, fc1_b, ws + o_z);
    mm_naive_bt_k<3><<<(32*1845 + 255)/256, 256, 0, stream>>>(
        ws + o_z, 600, 32, 600, fc2_W, 1845, fc2_b, outf);
}